// Round 17
// baseline (405.267 us; speedup 1.0000x reference)
//
#include <hip/hip_runtime.h>
#include <hip/hip_bf16.h>
#include <stdint.h>
#include <math.h>

#define NT_ 65536
#define BGRAPH 128
#define NNODE 512
#define DIM 128
#define HID 128
#define H2 256
#define EDGES 1048576
#define EPG 8192
#define KSEL 256
#define OUTC 10

typedef float v2f __attribute__((ext_vector_type(2)));

// ---------------- fused per-graph CSR build: hist -> scan -> fill -> rank ----------------
__global__ __launch_bounds__(512) void k_csr(const int* __restrict__ src, const int* __restrict__ dst,
                                             int* __restrict__ row_start, int* __restrict__ csr2) {
    __shared__ int hist[512];
    __shared__ int scan_s[512];
    __shared__ int cur[512];
    __shared__ int eids[EPG];
    const int g = blockIdx.x;
    const int t = threadIdx.x;
    const int base = g * EPG;
    const int nb = g * NNODE;
    hist[t] = 0;
    __syncthreads();
    #pragma unroll
    for (int j = t; j < EPG; j += 512) {
        int d = dst[base + j] - nb;
        atomicAdd(&hist[d], 1);
    }
    __syncthreads();
    int v = hist[t];
    scan_s[t] = v;
    __syncthreads();
    for (int off = 1; off < 512; off <<= 1) {
        int u = (t >= off) ? scan_s[t - off] : 0;
        __syncthreads();
        scan_s[t] += u;
        __syncthreads();
    }
    int excl = scan_s[t] - v;
    row_start[nb + t] = base + excl;
    cur[t] = excl;
    if (g == BGRAPH - 1 && t == 511) row_start[NT_] = EDGES;
    __syncthreads();
    #pragma unroll
    for (int j = t; j < EPG; j += 512) {
        int d = dst[base + j] - nb;
        int pos = atomicAdd(&cur[d], 1);
        eids[pos] = (d << 16) | j;
    }
    __syncthreads();
    #pragma unroll
    for (int p = t; p < EPG; p += 512) {
        int packed = eids[p];
        int j = packed & 0xFFFF;
        int d = packed >> 16;
        int beg = scan_s[d] - hist[d];
        int end = scan_s[d];
        int rank = 0;
        for (int q = beg; q < end; ++q) rank += (int)((eids[q] & 0xFFFF) < j);
        csr2[base + beg + rank] = src[base + j];
    }
}

// ---------------- gather + GIN combine: xin = (1+eps)*x + agg ----------------
__global__ __launch_bounds__(256) void k_aggcomb(const float* __restrict__ X,
        const int* __restrict__ row_start, const int* __restrict__ csr_src,
        const float* __restrict__ epss, int l, float* __restrict__ XIN) {
    int bid = blockIdx.x;
    int wg = (bid & 7) * 1024 + (bid >> 3);
    int wave = threadIdx.x >> 6;
    int lane = threadIdx.x & 63;
    int half = lane >> 5;
    int l32 = lane & 31;
    int n = wg * 8 + wave * 2 + half;
    int beg = row_start[n], end = row_start[n + 1];
    const size_t co = (size_t)(l32 * 4);
    const float ep = __fadd_rn(1.0f, epss[l]);
    float a0 = 0.f, a1 = 0.f, a2 = 0.f, a3 = 0.f;
    int p = beg;
    for (; p + 8 <= end; p += 8) {
        int n0 = csr_src[p+0], n1 = csr_src[p+1], n2 = csr_src[p+2], n3 = csr_src[p+3];
        int n4 = csr_src[p+4], n5 = csr_src[p+5], n6 = csr_src[p+6], n7 = csr_src[p+7];
        float4 v0 = *(const float4*)(X + (size_t)n0 * DIM + co);
        float4 v1 = *(const float4*)(X + (size_t)n1 * DIM + co);
        float4 v2 = *(const float4*)(X + (size_t)n2 * DIM + co);
        float4 v3 = *(const float4*)(X + (size_t)n3 * DIM + co);
        float4 v4 = *(const float4*)(X + (size_t)n4 * DIM + co);
        float4 v5 = *(const float4*)(X + (size_t)n5 * DIM + co);
        float4 v6 = *(const float4*)(X + (size_t)n6 * DIM + co);
        float4 v7 = *(const float4*)(X + (size_t)n7 * DIM + co);
        a0 = __fadd_rn(a0, v0.x); a1 = __fadd_rn(a1, v0.y); a2 = __fadd_rn(a2, v0.z); a3 = __fadd_rn(a3, v0.w);
        a0 = __fadd_rn(a0, v1.x); a1 = __fadd_rn(a1, v1.y); a2 = __fadd_rn(a2, v1.z); a3 = __fadd_rn(a3, v1.w);
        a0 = __fadd_rn(a0, v2.x); a1 = __fadd_rn(a1, v2.y); a2 = __fadd_rn(a2, v2.z); a3 = __fadd_rn(a3, v2.w);
        a0 = __fadd_rn(a0, v3.x); a1 = __fadd_rn(a1, v3.y); a2 = __fadd_rn(a2, v3.z); a3 = __fadd_rn(a3, v3.w);
        a0 = __fadd_rn(a0, v4.x); a1 = __fadd_rn(a1, v4.y); a2 = __fadd_rn(a2, v4.z); a3 = __fadd_rn(a3, v4.w);
        a0 = __fadd_rn(a0, v5.x); a1 = __fadd_rn(a1, v5.y); a2 = __fadd_rn(a2, v5.z); a3 = __fadd_rn(a3, v5.w);
        a0 = __fadd_rn(a0, v6.x); a1 = __fadd_rn(a1, v6.y); a2 = __fadd_rn(a2, v6.z); a3 = __fadd_rn(a3, v6.w);
        a0 = __fadd_rn(a0, v7.x); a1 = __fadd_rn(a1, v7.y); a2 = __fadd_rn(a2, v7.z); a3 = __fadd_rn(a3, v7.w);
    }
    for (; p < end; ++p) {
        int nbr = csr_src[p];
        float4 v = *(const float4*)(X + (size_t)nbr * DIM + co);
        a0 = __fadd_rn(a0, v.x); a1 = __fadd_rn(a1, v.y); a2 = __fadd_rn(a2, v.z); a3 = __fadd_rn(a3, v.w);
    }
    float4 xv = *(const float4*)(X + (size_t)n * DIM + co);
    float4 o;
    o.x = __fadd_rn(__fmul_rn(ep, xv.x), a0);
    o.y = __fadd_rn(__fmul_rn(ep, xv.y), a1);
    o.z = __fadd_rn(__fmul_rn(ep, xv.z), a2);
    o.w = __fadd_rn(__fmul_rn(ep, xv.w), a3);
    *(float4*)(XIN + (size_t)n * DIM + co) = o;
}

// ---------------- GEMM1: 128x128 tile, BK=32, dbuf ping-pong (4 kt iters) ----------------
__global__ __launch_bounds__(256) void k_gemm1(const float* __restrict__ XIN,
        const float* __restrict__ Ws1, const float* __restrict__ bs1,
        const float* __restrict__ g1s, const float* __restrict__ be1s, const float* __restrict__ rm1s,
        const float* __restrict__ rv1s, int l, float* __restrict__ H1out) {
    __shared__ float As[2][32][132];
    __shared__ float Bs[2][32][132];
    const float* W1  = Ws1 + (size_t)l * DIM * H2;
    const float* b1  = bs1 + l * H2;
    const float* g1  = g1s + l * H2;
    const float* be1 = be1s + l * H2;
    const float* rm1 = rm1s + l * H2;
    const float* rv1 = rv1s + l * H2;
    int bid = blockIdx.x;
    int wg = (bid & 7) * 128 + (bid >> 3);
    const int mbase = (wg >> 1) * 128;
    const int nbase = (wg & 1) * 128;
    const int tid = threadIdx.x;
    const int srow = tid >> 1;           // 0..127
    const int sk   = (tid & 1) * 16;     // 0 or 16
    const int bk   = tid >> 3;           // 0..31
    const int bc   = (tid & 7) * 16;     // 0..112
    const int ty = tid >> 4;
    const int tx = tid & 15;
    v2f acc[8][4] = {};
    const float* xr = XIN + (size_t)(mbase + srow) * DIM + sk;
    float4 pa[4], pw[4];
    #pragma unroll
    for (int q = 0; q < 4; ++q) pa[q] = *(const float4*)(xr + q * 4);
    {
        const float* wrow = W1 + (size_t)bk * H2 + nbase + bc;
        #pragma unroll
        for (int q = 0; q < 4; ++q) pw[q] = *(const float4*)(wrow + q * 4);
    }
    #pragma unroll
    for (int q = 0; q < 4; ++q) {
        As[0][sk + q*4 + 0][srow] = pa[q].x;
        As[0][sk + q*4 + 1][srow] = pa[q].y;
        As[0][sk + q*4 + 2][srow] = pa[q].z;
        As[0][sk + q*4 + 3][srow] = pa[q].w;
        *(float4*)&Bs[0][bk][bc + q * 4] = pw[q];
    }
    __syncthreads();
    int cur = 0;
    for (int kt = 0; kt < DIM; kt += 32) {
        const int nxt = kt + 32;
        if (nxt < DIM) {
            #pragma unroll
            for (int q = 0; q < 4; ++q) pa[q] = *(const float4*)(xr + nxt + q * 4);
            const float* wrow = W1 + (size_t)(nxt + bk) * H2 + nbase + bc;
            #pragma unroll
            for (int q = 0; q < 4; ++q) pw[q] = *(const float4*)(wrow + q * 4);
        }
        #pragma unroll
        for (int kk = 0; kk < 32; ++kk) {
            const float4 aA = *(const float4*)&As[cur][kk][ty * 8];
            const float4 aB = *(const float4*)&As[cur][kk][ty * 8 + 4];
            const float4 b0 = *(const float4*)&Bs[cur][kk][tx * 4];
            const float4 b1v = *(const float4*)&Bs[cur][kk][tx * 4 + 64];
            v2f b00; b00[0] = b0.x;  b00[1] = b0.y;
            v2f b01; b01[0] = b0.z;  b01[1] = b0.w;
            v2f b10; b10[0] = b1v.x; b10[1] = b1v.y;
            v2f b11; b11[0] = b1v.z; b11[1] = b1v.w;
            const float arr[8] = {aA.x, aA.y, aA.z, aA.w, aB.x, aB.y, aB.z, aB.w};
            #pragma unroll
            for (int i = 0; i < 8; ++i) {
                v2f ai; ai[0] = arr[i]; ai[1] = arr[i];
                acc[i][0] = __builtin_elementwise_fma(ai, b00, acc[i][0]);
                acc[i][1] = __builtin_elementwise_fma(ai, b01, acc[i][1]);
                acc[i][2] = __builtin_elementwise_fma(ai, b10, acc[i][2]);
                acc[i][3] = __builtin_elementwise_fma(ai, b11, acc[i][3]);
            }
        }
        if (nxt < DIM) {
            const int nb = cur ^ 1;
            #pragma unroll
            for (int q = 0; q < 4; ++q) {
                As[nb][sk + q*4 + 0][srow] = pa[q].x;
                As[nb][sk + q*4 + 1][srow] = pa[q].y;
                As[nb][sk + q*4 + 2][srow] = pa[q].z;
                As[nb][sk + q*4 + 3][srow] = pa[q].w;
                *(float4*)&Bs[nb][bk][bc + q * 4] = pw[q];
            }
            __syncthreads();
        }
        cur ^= 1;
    }
    const int gc = nbase + tx * 4;
    float bb[8], iv[8], gg[8], rr[8], ee[8];
    #pragma unroll
    for (int j = 0; j < 8; ++j) {
        int c = (j < 4) ? (gc + j) : (gc + 60 + j);
        bb[j] = b1[c];
        iv[j] = __fdiv_rn(1.0f, __fsqrt_rn(__fadd_rn(rv1[c], 1e-5f)));
        gg[j] = g1[c];
        rr[j] = rm1[c];
        ee[j] = be1[c];
    }
    #pragma unroll
    for (int i = 0; i < 8; ++i) {
        const int gr = mbase + ty * 8 + i;
        float cv[8] = {acc[i][0][0], acc[i][0][1], acc[i][1][0], acc[i][1][1],
                       acc[i][2][0], acc[i][2][1], acc[i][3][0], acc[i][3][1]};
        float r[8];
        #pragma unroll
        for (int j = 0; j < 8; ++j) {
            float t = __fadd_rn(cv[j], bb[j]);
            t = __fsub_rn(t, rr[j]); t = __fmul_rn(t, iv[j]);
            t = __fmul_rn(t, gg[j]); t = __fadd_rn(t, ee[j]);
            r[j] = fmaxf(t, 0.f);
        }
        float4 o0; o0.x = r[0]; o0.y = r[1]; o0.z = r[2]; o0.w = r[3];
        float4 o1; o1.x = r[4]; o1.y = r[5]; o1.z = r[6]; o1.w = r[7];
        *(float4*)(H1out + (size_t)gr * H2 + gc)      = o0;
        *(float4*)(H1out + (size_t)gr * H2 + gc + 64) = o1;
    }
}

// ---------------- GEMM2: 128x128 tile, BK=32, dbuf ping-pong (8 kt iters) ----------------
__global__ __launch_bounds__(256) void k_gemm2(const float* __restrict__ H1, const float* __restrict__ Ws2,
        const float* __restrict__ bs2, const float* __restrict__ gbn, const float* __restrict__ bbn,
        const float* __restrict__ rmbn, const float* __restrict__ rvbn, int l, float* __restrict__ Xout) {
    __shared__ float As[2][32][132];
    __shared__ float Bs[2][32][132];
    const float* W2 = Ws2 + (size_t)l * H2 * HID;
    const float* b2 = bs2 + l * HID;
    const float* g  = gbn + l * HID;
    const float* be = bbn + l * HID;
    const float* rm = rmbn + l * HID;
    const float* rv = rvbn + l * HID;
    int bid = blockIdx.x;
    int wg = (bid & 7) * 64 + (bid >> 3);
    const int mbase = wg * 128;
    const int tid = threadIdx.x;
    const int srow = tid >> 1;
    const int sk   = (tid & 1) * 16;
    const int bk   = tid >> 3;           // 0..31
    const int bc   = (tid & 7) * 16;     // 0..112
    const int ty = tid >> 4;
    const int tx = tid & 15;
    v2f acc[8][4] = {};
    const float* hr = H1 + (size_t)(mbase + srow) * H2 + sk;
    float4 pa[4], pw[4];
    #pragma unroll
    for (int q = 0; q < 4; ++q) pa[q] = *(const float4*)(hr + q * 4);
    {
        const float* wrow = W2 + (size_t)bk * HID + bc;
        #pragma unroll
        for (int q = 0; q < 4; ++q) pw[q] = *(const float4*)(wrow + q * 4);
    }
    #pragma unroll
    for (int q = 0; q < 4; ++q) {
        As[0][sk + q*4 + 0][srow] = pa[q].x;
        As[0][sk + q*4 + 1][srow] = pa[q].y;
        As[0][sk + q*4 + 2][srow] = pa[q].z;
        As[0][sk + q*4 + 3][srow] = pa[q].w;
        *(float4*)&Bs[0][bk][bc + q * 4] = pw[q];
    }
    __syncthreads();
    int cur = 0;
    for (int kt = 0; kt < H2; kt += 32) {
        const int nxt = kt + 32;
        if (nxt < H2) {
            #pragma unroll
            for (int q = 0; q < 4; ++q) pa[q] = *(const float4*)(hr + nxt + q * 4);
            const float* wrow = W2 + (size_t)(nxt + bk) * HID + bc;
            #pragma unroll
            for (int q = 0; q < 4; ++q) pw[q] = *(const float4*)(wrow + q * 4);
        }
        #pragma unroll
        for (int kk = 0; kk < 32; ++kk) {
            const float4 aA = *(const float4*)&As[cur][kk][ty * 8];
            const float4 aB = *(const float4*)&As[cur][kk][ty * 8 + 4];
            const float4 b0 = *(const float4*)&Bs[cur][kk][tx * 4];
            const float4 b1v = *(const float4*)&Bs[cur][kk][tx * 4 + 64];
            v2f b00; b00[0] = b0.x;  b00[1] = b0.y;
            v2f b01; b01[0] = b0.z;  b01[1] = b0.w;
            v2f b10; b10[0] = b1v.x; b10[1] = b1v.y;
            v2f b11; b11[0] = b1v.z; b11[1] = b1v.w;
            const float arr[8] = {aA.x, aA.y, aA.z, aA.w, aB.x, aB.y, aB.z, aB.w};
            #pragma unroll
            for (int i = 0; i < 8; ++i) {
                v2f ai; ai[0] = arr[i]; ai[1] = arr[i];
                acc[i][0] = __builtin_elementwise_fma(ai, b00, acc[i][0]);
                acc[i][1] = __builtin_elementwise_fma(ai, b01, acc[i][1]);
                acc[i][2] = __builtin_elementwise_fma(ai, b10, acc[i][2]);
                acc[i][3] = __builtin_elementwise_fma(ai, b11, acc[i][3]);
            }
        }
        if (nxt < H2) {
            const int nb = cur ^ 1;
            #pragma unroll
            for (int q = 0; q < 4; ++q) {
                As[nb][sk + q*4 + 0][srow] = pa[q].x;
                As[nb][sk + q*4 + 1][srow] = pa[q].y;
                As[nb][sk + q*4 + 2][srow] = pa[q].z;
                As[nb][sk + q*4 + 3][srow] = pa[q].w;
                *(float4*)&Bs[nb][bk][bc + q * 4] = pw[q];
            }
            __syncthreads();
        }
        cur ^= 1;
    }
    const int gc = tx * 4;
    float bb[8], iv[8], gg[8], rr[8], ee[8];
    #pragma unroll
    for (int j = 0; j < 8; ++j) {
        int c = (j < 4) ? (gc + j) : (gc + 60 + j);
        bb[j] = b2[c];
        iv[j] = __fdiv_rn(1.0f, __fsqrt_rn(__fadd_rn(rv[c], 1e-5f)));
        gg[j] = g[c];
        rr[j] = rm[c];
        ee[j] = be[c];
    }
    #pragma unroll
    for (int i = 0; i < 8; ++i) {
        const int gr = mbase + ty * 8 + i;
        float cv[8] = {acc[i][0][0], acc[i][0][1], acc[i][1][0], acc[i][1][1],
                       acc[i][2][0], acc[i][2][1], acc[i][3][0], acc[i][3][1]};
        float r[8];
        #pragma unroll
        for (int j = 0; j < 8; ++j) {
            float t = __fadd_rn(cv[j], bb[j]);
            t = __fsub_rn(t, rr[j]); t = __fmul_rn(t, iv[j]);
            t = __fmul_rn(t, gg[j]); t = __fadd_rn(t, ee[j]);
            r[j] = fmaxf(t, 0.f);
        }
        float4 o0; o0.x = r[0]; o0.y = r[1]; o0.z = r[2]; o0.w = r[3];
        float4 o1; o1.x = r[4]; o1.y = r[5]; o1.z = r[6]; o1.w = r[7];
        *(float4*)(Xout + (size_t)gr * HID + gc)      = o0;
        *(float4*)(Xout + (size_t)gr * HID + gc + 64) = o1;
    }
}

// ---------------- per-node projections: y = x.Wrel, z = x.Wroot ----------------
__global__ __launch_bounds__(256) void k_ydot(const float* __restrict__ X,
        const float* __restrict__ Wrel, const float* __restrict__ Wroot,
        float* __restrict__ Y, float* __restrict__ Z) {
    int wave = threadIdx.x >> 6;
    int lane = threadIdx.x & 63;
    int n = blockIdx.x * 4 + wave;
    const float2 xv = *(const float2*)(X + (size_t)n * HID + lane * 2);
    const float2 wr = *(const float2*)(Wrel + lane * 2);
    const float2 wo = *(const float2*)(Wroot + lane * 2);
    float p1 = __fmaf_rn(xv.y, wr.y, __fmul_rn(xv.x, wr.x));
    float p2 = __fmaf_rn(xv.y, wo.y, __fmul_rn(xv.x, wo.x));
    #pragma unroll
    for (int off = 1; off <= 32; off <<= 1) {
        p1 += __shfl_xor(p1, off);
        p2 += __shfl_xor(p2, off);
    }
    if (lane == 0) { Y[n] = p1; Z[n] = p2; }
}

// ---------------- score via scalar gather ----------------
__global__ __launch_bounds__(256) void k_scorelite(const float* __restrict__ Y, const float* __restrict__ Z,
        const int* __restrict__ row_start, const int* __restrict__ csr_src,
        const float* __restrict__ brel, float* __restrict__ S) {
    int n = blockIdx.x * 256 + threadIdx.x;
    int beg = row_start[n], end = row_start[n + 1];
    float p1 = 0.f;
    for (int p = beg; p < end; ++p) p1 = __fadd_rn(p1, Y[csr_src[p]]);
    float pp = __fadd_rn(__fadd_rn(p1, brel[0]), Z[n]);
    const float PC = 7.90531110763549805f;   // XLA fast-tanh input clamp -> plateau tie class
    float s;
    if (pp >= PC)       s = 1.0f;
    else if (pp <= -PC) s = -1.0f;
    else                s = (float)tanh((double)pp);
    S[n] = s;
}

// ---------------- SAGPool top-K + pool + head (fused) ----------------
__global__ __launch_bounds__(512) void k_poolhead(const float* __restrict__ X, const float* __restrict__ S,
        const float* __restrict__ W1, const float* __restrict__ b1,
        const float* __restrict__ gh, const float* __restrict__ beh,
        const float* __restrict__ rmh, const float* __restrict__ rvh,
        const float* __restrict__ W2, const float* __restrict__ b2,
        float* __restrict__ EMB, float* __restrict__ LOGITS) {
    __shared__ unsigned key[512];
    __shared__ double w[512];
    __shared__ double red[4][128];
    __shared__ double embs[128];
    __shared__ double hbuf[128];
    const int b = blockIdx.x, tid = threadIdx.x;
    float v = S[b * NNODE + tid];
    unsigned u = __float_as_uint(v);
    unsigned o = (u & 0x80000000u) ? ~u : (u | 0x80000000u);
    key[tid] = o;
    __syncthreads();
    int rank = 0;
    for (int j = 0; j < NNODE; ++j) {
        unsigned kj = key[j];
        rank += (int)((kj > o) || (kj == o && j < tid));
    }
    w[tid] = (rank < KSEL) ? (double)v : 0.0;
    __syncthreads();
    const int jgrp = tid >> 7;
    const int col = tid & 127;
    double acc = 0.0;
    for (int i = jgrp; i < NNODE; i += 4) {
        acc += (double)X[((size_t)b * NNODE + i) * HID + col] * w[i];
    }
    red[jgrp][col] = acc;
    __syncthreads();
    if (jgrp == 0) {
        double e = red[0][col] + red[1][col] + red[2][col] + red[3][col];
        EMB[b * HID + col] = (float)e;
        embs[col] = e;
    }
    __syncthreads();
    // head: 128 active threads
    if (tid < 128) {
        double a = 0.0;
        for (int k = 0; k < HID; ++k) a += embs[k] * (double)W1[k * HID + tid];
        a += (double)b1[tid];
        double inv = 1.0 / sqrt((double)rvh[tid] + 1e-5);
        a = (a - (double)rmh[tid]) * inv * (double)gh[tid] + (double)beh[tid];
        hbuf[tid] = fmax(a, 0.0);
    }
    __syncthreads();
    if (tid < OUTC) {
        double a2 = (double)b2[tid];
        for (int k = 0; k < HID; ++k) a2 += hbuf[k] * (double)W2[k * OUTC + tid];
        LOGITS[b * OUTC + tid] = (float)a2;
    }
}

extern "C" void kernel_launch(void* const* d_in, const int* in_sizes, int n_in,
                              void* d_out, int out_size, void* d_ws, size_t ws_size,
                              hipStream_t stream) {
    const float* x     = (const float*)d_in[0];
    const int*   edge  = (const int*)d_in[1];
    const int*   src   = edge;
    const int*   dst   = edge + EDGES;
    const float* epss  = (const float*)d_in[3];
    const float* Ws1   = (const float*)d_in[4];
    const float* bs1   = (const float*)d_in[5];
    const float* g1s   = (const float*)d_in[6];
    const float* be1s  = (const float*)d_in[7];
    const float* rm1s  = (const float*)d_in[8];
    const float* rv1s  = (const float*)d_in[9];
    const float* Ws2   = (const float*)d_in[10];
    const float* bs2   = (const float*)d_in[11];
    const float* gbn   = (const float*)d_in[12];
    const float* bbn   = (const float*)d_in[13];
    const float* rmbn  = (const float*)d_in[14];
    const float* rvbn  = (const float*)d_in[15];
    const float* Wrel  = (const float*)d_in[16];
    const float* brel  = (const float*)d_in[17];
    const float* Wroot = (const float*)d_in[18];
    const float* W_lin1= (const float*)d_in[19];
    const float* b_lin1= (const float*)d_in[20];
    const float* g_h   = (const float*)d_in[21];
    const float* be_h  = (const float*)d_in[22];
    const float* rm_h  = (const float*)d_in[23];
    const float* rv_h  = (const float*)d_in[24];
    const float* W_lin2= (const float*)d_in[25];
    const float* b_lin2= (const float*)d_in[26];

    char* ws = (char*)d_ws;
    float*  x_cur    = (float*) (ws);                    // 32 MB
    float*  xin      = (float*) (ws + 33554432);         // 32 MB
    float*  h1       = (float*) (ws + 67108864);         // 64 MB
    float*  s32      = (float*) (ws + 134217728);        // 256 KB
    float*  ybuf     = (float*) (ws + 134479872);        // 256 KB
    float*  zbuf     = (float*) (ws + 134742016);        // 256 KB
    int*    row_start= (int*)   (ws + 135004160);        // 280 KB (NT_+1 ints)
    int*    csr2     = (int*)   (ws + 135290880);        // 4 MB (edge-order srcs)

    float* emb    = (float*)d_out;
    float* logits = (float*)d_out + BGRAPH * HID;

    // ---- fused per-graph CSR build ----
    k_csr<<<BGRAPH, 512, 0, stream>>>(src, dst, row_start, csr2);

    // ---- layer 0 ----
    k_aggcomb<<<NT_ / 8, 256, 0, stream>>>(x, row_start, csr2, epss, 0, xin);
    k_gemm1<<<1024, 256, 0, stream>>>(xin, Ws1, bs1, g1s, be1s, rm1s, rv1s, 0, h1);
    k_gemm2<<<512, 256, 0, stream>>>(h1, Ws2, bs2, gbn, bbn, rmbn, rvbn, 0, x_cur);
    // ---- layer 1 ----
    k_aggcomb<<<NT_ / 8, 256, 0, stream>>>(x_cur, row_start, csr2, epss, 1, xin);
    k_gemm1<<<1024, 256, 0, stream>>>(xin, Ws1, bs1, g1s, be1s, rm1s, rv1s, 1, h1);
    k_gemm2<<<512, 256, 0, stream>>>(h1, Ws2, bs2, gbn, bbn, rmbn, rvbn, 1, x_cur);
    // ---- scoring via scalar projections, pool+head ----
    k_ydot<<<NT_ / 4, 256, 0, stream>>>(x_cur, Wrel, Wroot, ybuf, zbuf);
    k_scorelite<<<NT_ / 256, 256, 0, stream>>>(ybuf, zbuf, row_start, csr2, brel, s32);
    k_poolhead<<<BGRAPH, 512, 0, stream>>>(x_cur, s32, W_lin1, b_lin1, g_h, be_h, rm_h, rv_h,
                                           W_lin2, b_lin2, emb, logits);
}

// Round 18
// 387.832 us; speedup vs baseline: 1.0450x; 1.0450x over previous
//
#include <hip/hip_runtime.h>
#include <hip/hip_bf16.h>
#include <stdint.h>
#include <math.h>

#define NT_ 65536
#define BGRAPH 128
#define NNODE 512
#define DIM 128
#define HID 128
#define H2 256
#define EDGES 1048576
#define EPG 8192
#define KSEL 256
#define OUTC 10

typedef float v2f __attribute__((ext_vector_type(2)));

// ---------------- fused per-graph CSR build: hist -> scan -> fill -> rank ----------------
__global__ __launch_bounds__(512) void k_csr(const int* __restrict__ src, const int* __restrict__ dst,
                                             int* __restrict__ row_start, int* __restrict__ csr2) {
    __shared__ int hist[512];
    __shared__ int scan_s[512];
    __shared__ int cur[512];
    __shared__ int eids[EPG];
    const int g = blockIdx.x;
    const int t = threadIdx.x;
    const int base = g * EPG;
    const int nb = g * NNODE;
    hist[t] = 0;
    __syncthreads();
    #pragma unroll
    for (int j = t; j < EPG; j += 512) {
        int d = dst[base + j] - nb;
        atomicAdd(&hist[d], 1);
    }
    __syncthreads();
    int v = hist[t];
    scan_s[t] = v;
    __syncthreads();
    for (int off = 1; off < 512; off <<= 1) {
        int u = (t >= off) ? scan_s[t - off] : 0;
        __syncthreads();
        scan_s[t] += u;
        __syncthreads();
    }
    int excl = scan_s[t] - v;
    row_start[nb + t] = base + excl;
    cur[t] = excl;
    if (g == BGRAPH - 1 && t == 511) row_start[NT_] = EDGES;
    __syncthreads();
    #pragma unroll
    for (int j = t; j < EPG; j += 512) {
        int d = dst[base + j] - nb;
        int pos = atomicAdd(&cur[d], 1);
        eids[pos] = (d << 16) | j;
    }
    __syncthreads();
    #pragma unroll
    for (int p = t; p < EPG; p += 512) {
        int packed = eids[p];
        int j = packed & 0xFFFF;
        int d = packed >> 16;
        int beg = scan_s[d] - hist[d];
        int end = scan_s[d];
        int rank = 0;
        for (int q = beg; q < end; ++q) rank += (int)((eids[q] & 0xFFFF) < j);
        csr2[base + beg + rank] = src[base + j];
    }
}

// ---------------- gather + GIN combine: xin = (1+eps)*x + agg ----------------
__global__ __launch_bounds__(256) void k_aggcomb(const float* __restrict__ X,
        const int* __restrict__ row_start, const int* __restrict__ csr_src,
        const float* __restrict__ epss, int l, float* __restrict__ XIN) {
    int bid = blockIdx.x;
    int wg = (bid & 7) * 1024 + (bid >> 3);
    int wave = threadIdx.x >> 6;
    int lane = threadIdx.x & 63;
    int half = lane >> 5;
    int l32 = lane & 31;
    int n = wg * 8 + wave * 2 + half;
    int beg = row_start[n], end = row_start[n + 1];
    const size_t co = (size_t)(l32 * 4);
    const float ep = __fadd_rn(1.0f, epss[l]);
    float a0 = 0.f, a1 = 0.f, a2 = 0.f, a3 = 0.f;
    int p = beg;
    for (; p + 8 <= end; p += 8) {
        int n0 = csr_src[p+0], n1 = csr_src[p+1], n2 = csr_src[p+2], n3 = csr_src[p+3];
        int n4 = csr_src[p+4], n5 = csr_src[p+5], n6 = csr_src[p+6], n7 = csr_src[p+7];
        float4 v0 = *(const float4*)(X + (size_t)n0 * DIM + co);
        float4 v1 = *(const float4*)(X + (size_t)n1 * DIM + co);
        float4 v2 = *(const float4*)(X + (size_t)n2 * DIM + co);
        float4 v3 = *(const float4*)(X + (size_t)n3 * DIM + co);
        float4 v4 = *(const float4*)(X + (size_t)n4 * DIM + co);
        float4 v5 = *(const float4*)(X + (size_t)n5 * DIM + co);
        float4 v6 = *(const float4*)(X + (size_t)n6 * DIM + co);
        float4 v7 = *(const float4*)(X + (size_t)n7 * DIM + co);
        a0 = __fadd_rn(a0, v0.x); a1 = __fadd_rn(a1, v0.y); a2 = __fadd_rn(a2, v0.z); a3 = __fadd_rn(a3, v0.w);
        a0 = __fadd_rn(a0, v1.x); a1 = __fadd_rn(a1, v1.y); a2 = __fadd_rn(a2, v1.z); a3 = __fadd_rn(a3, v1.w);
        a0 = __fadd_rn(a0, v2.x); a1 = __fadd_rn(a1, v2.y); a2 = __fadd_rn(a2, v2.z); a3 = __fadd_rn(a3, v2.w);
        a0 = __fadd_rn(a0, v3.x); a1 = __fadd_rn(a1, v3.y); a2 = __fadd_rn(a2, v3.z); a3 = __fadd_rn(a3, v3.w);
        a0 = __fadd_rn(a0, v4.x); a1 = __fadd_rn(a1, v4.y); a2 = __fadd_rn(a2, v4.z); a3 = __fadd_rn(a3, v4.w);
        a0 = __fadd_rn(a0, v5.x); a1 = __fadd_rn(a1, v5.y); a2 = __fadd_rn(a2, v5.z); a3 = __fadd_rn(a3, v5.w);
        a0 = __fadd_rn(a0, v6.x); a1 = __fadd_rn(a1, v6.y); a2 = __fadd_rn(a2, v6.z); a3 = __fadd_rn(a3, v6.w);
        a0 = __fadd_rn(a0, v7.x); a1 = __fadd_rn(a1, v7.y); a2 = __fadd_rn(a2, v7.z); a3 = __fadd_rn(a3, v7.w);
    }
    for (; p < end; ++p) {
        int nbr = csr_src[p];
        float4 v = *(const float4*)(X + (size_t)nbr * DIM + co);
        a0 = __fadd_rn(a0, v.x); a1 = __fadd_rn(a1, v.y); a2 = __fadd_rn(a2, v.z); a3 = __fadd_rn(a3, v.w);
    }
    float4 xv = *(const float4*)(X + (size_t)n * DIM + co);
    float4 o;
    o.x = __fadd_rn(__fmul_rn(ep, xv.x), a0);
    o.y = __fadd_rn(__fmul_rn(ep, xv.y), a1);
    o.z = __fadd_rn(__fmul_rn(ep, xv.z), a2);
    o.w = __fadd_rn(__fmul_rn(ep, xv.w), a3);
    *(float4*)(XIN + (size_t)n * DIM + co) = o;
}

// ---------------- GEMM1: h1 = relu(bn(XIN @ W1 + b1)), 128x128 tile, BK=16, dbuf ----------------
__global__ __launch_bounds__(256) void k_gemm1(const float* __restrict__ XIN,
        const float* __restrict__ Ws1, const float* __restrict__ bs1,
        const float* __restrict__ g1s, const float* __restrict__ be1s, const float* __restrict__ rm1s,
        const float* __restrict__ rv1s, int l, float* __restrict__ H1out) {
    __shared__ float As[2][16][132];
    __shared__ float Bs[2][16][132];
    const float* W1  = Ws1 + (size_t)l * DIM * H2;
    const float* b1  = bs1 + l * H2;
    const float* g1  = g1s + l * H2;
    const float* be1 = be1s + l * H2;
    const float* rm1 = rm1s + l * H2;
    const float* rv1 = rv1s + l * H2;
    int bid = blockIdx.x;
    int wg = (bid & 7) * 128 + (bid >> 3);
    const int mbase = (wg >> 1) * 128;
    const int nbase = (wg & 1) * 128;
    const int tid = threadIdx.x;
    const int srow = tid >> 1;
    const int sk   = (tid & 1) * 8;
    const int bk   = tid >> 4;
    const int bc   = (tid & 15) * 4;
    const int ty = tid >> 4;
    const int tx = tid & 15;
    v2f acc[8][4] = {};
    const float* xr = XIN + (size_t)(mbase + srow) * DIM + sk;
    float4 px0, px1, pw0, pw1;
    px0 = *(const float4*)(xr);     px1 = *(const float4*)(xr + 4);
    {
        const float* wrow = W1 + (size_t)bk * H2 + nbase;
        pw0 = *(const float4*)(wrow + bc); pw1 = *(const float4*)(wrow + bc + 64);
    }
    As[0][sk + 0][srow] = px0.x;
    As[0][sk + 1][srow] = px0.y;
    As[0][sk + 2][srow] = px0.z;
    As[0][sk + 3][srow] = px0.w;
    As[0][sk + 4][srow] = px1.x;
    As[0][sk + 5][srow] = px1.y;
    As[0][sk + 6][srow] = px1.z;
    As[0][sk + 7][srow] = px1.w;
    *(float4*)&Bs[0][bk][bc]      = pw0;
    *(float4*)&Bs[0][bk][bc + 64] = pw1;
    __syncthreads();
    int cur = 0;
    for (int kt = 0; kt < DIM; kt += 16) {
        const int nxt = kt + 16;
        if (nxt < DIM) {
            px0 = *(const float4*)(xr + nxt);     px1 = *(const float4*)(xr + nxt + 4);
            const float* wrow = W1 + (size_t)(nxt + bk) * H2 + nbase;
            pw0 = *(const float4*)(wrow + bc); pw1 = *(const float4*)(wrow + bc + 64);
        }
        #pragma unroll
        for (int kk = 0; kk < 16; ++kk) {
            const float4 aA = *(const float4*)&As[cur][kk][ty * 8];
            const float4 aB = *(const float4*)&As[cur][kk][ty * 8 + 4];
            const float4 b0 = *(const float4*)&Bs[cur][kk][tx * 4];
            const float4 b1v = *(const float4*)&Bs[cur][kk][tx * 4 + 64];
            v2f b00; b00[0] = b0.x;  b00[1] = b0.y;
            v2f b01; b01[0] = b0.z;  b01[1] = b0.w;
            v2f b10; b10[0] = b1v.x; b10[1] = b1v.y;
            v2f b11; b11[0] = b1v.z; b11[1] = b1v.w;
            const float arr[8] = {aA.x, aA.y, aA.z, aA.w, aB.x, aB.y, aB.z, aB.w};
            #pragma unroll
            for (int i = 0; i < 8; ++i) {
                v2f ai; ai[0] = arr[i]; ai[1] = arr[i];
                acc[i][0] = __builtin_elementwise_fma(ai, b00, acc[i][0]);
                acc[i][1] = __builtin_elementwise_fma(ai, b01, acc[i][1]);
                acc[i][2] = __builtin_elementwise_fma(ai, b10, acc[i][2]);
                acc[i][3] = __builtin_elementwise_fma(ai, b11, acc[i][3]);
            }
        }
        if (nxt < DIM) {
            const int nb = cur ^ 1;
            As[nb][sk + 0][srow] = px0.x;
            As[nb][sk + 1][srow] = px0.y;
            As[nb][sk + 2][srow] = px0.z;
            As[nb][sk + 3][srow] = px0.w;
            As[nb][sk + 4][srow] = px1.x;
            As[nb][sk + 5][srow] = px1.y;
            As[nb][sk + 6][srow] = px1.z;
            As[nb][sk + 7][srow] = px1.w;
            *(float4*)&Bs[nb][bk][bc]      = pw0;
            *(float4*)&Bs[nb][bk][bc + 64] = pw1;
            __syncthreads();
        }
        cur ^= 1;
    }
    const int gc = nbase + tx * 4;
    float bb[8], iv[8], gg[8], rr[8], ee[8];
    #pragma unroll
    for (int j = 0; j < 8; ++j) {
        int c = (j < 4) ? (gc + j) : (gc + 60 + j);
        bb[j] = b1[c];
        iv[j] = __fdiv_rn(1.0f, __fsqrt_rn(__fadd_rn(rv1[c], 1e-5f)));
        gg[j] = g1[c];
        rr[j] = rm1[c];
        ee[j] = be1[c];
    }
    #pragma unroll
    for (int i = 0; i < 8; ++i) {
        const int gr = mbase + ty * 8 + i;
        float cv[8] = {acc[i][0][0], acc[i][0][1], acc[i][1][0], acc[i][1][1],
                       acc[i][2][0], acc[i][2][1], acc[i][3][0], acc[i][3][1]};
        float r[8];
        #pragma unroll
        for (int j = 0; j < 8; ++j) {
            float t = __fadd_rn(cv[j], bb[j]);
            t = __fsub_rn(t, rr[j]); t = __fmul_rn(t, iv[j]);
            t = __fmul_rn(t, gg[j]); t = __fadd_rn(t, ee[j]);
            r[j] = fmaxf(t, 0.f);
        }
        float4 o0; o0.x = r[0]; o0.y = r[1]; o0.z = r[2]; o0.w = r[3];
        float4 o1; o1.x = r[4]; o1.y = r[5]; o1.z = r[6]; o1.w = r[7];
        *(float4*)(H1out + (size_t)gr * H2 + gc)      = o0;
        *(float4*)(H1out + (size_t)gr * H2 + gc + 64) = o1;
    }
}

// ---------------- GEMM2: 128x128 tile, BK=16, dbuf ping-pong ----------------
__global__ __launch_bounds__(256) void k_gemm2(const float* __restrict__ H1, const float* __restrict__ Ws2,
        const float* __restrict__ bs2, const float* __restrict__ gbn, const float* __restrict__ bbn,
        const float* __restrict__ rmbn, const float* __restrict__ rvbn, int l, float* __restrict__ Xout) {
    __shared__ float As[2][16][132];
    __shared__ float Bs[2][16][132];
    const float* W2 = Ws2 + (size_t)l * H2 * HID;
    const float* b2 = bs2 + l * HID;
    const float* g  = gbn + l * HID;
    const float* be = bbn + l * HID;
    const float* rm = rmbn + l * HID;
    const float* rv = rvbn + l * HID;
    int bid = blockIdx.x;
    int wg = (bid & 7) * 64 + (bid >> 3);
    const int mbase = wg * 128;
    const int tid = threadIdx.x;
    const int srow = tid >> 1;
    const int sk   = (tid & 1) * 8;
    const int bk   = tid >> 4;
    const int bc   = (tid & 15) * 4;
    const int ty = tid >> 4;
    const int tx = tid & 15;
    v2f acc[8][4] = {};
    const float* hr = H1 + (size_t)(mbase + srow) * H2 + sk;
    float4 ph0, ph1, pw0, pw1;
    ph0 = *(const float4*)(hr);     ph1 = *(const float4*)(hr + 4);
    {
        const float* wrow = W2 + (size_t)bk * HID;
        pw0 = *(const float4*)(wrow + bc); pw1 = *(const float4*)(wrow + bc + 64);
    }
    As[0][sk + 0][srow] = ph0.x;
    As[0][sk + 1][srow] = ph0.y;
    As[0][sk + 2][srow] = ph0.z;
    As[0][sk + 3][srow] = ph0.w;
    As[0][sk + 4][srow] = ph1.x;
    As[0][sk + 5][srow] = ph1.y;
    As[0][sk + 6][srow] = ph1.z;
    As[0][sk + 7][srow] = ph1.w;
    *(float4*)&Bs[0][bk][bc]      = pw0;
    *(float4*)&Bs[0][bk][bc + 64] = pw1;
    __syncthreads();
    int cur = 0;
    for (int kt = 0; kt < H2; kt += 16) {
        const int nxt = kt + 16;
        if (nxt < H2) {
            ph0 = *(const float4*)(hr + nxt);     ph1 = *(const float4*)(hr + nxt + 4);
            const float* wrow = W2 + (size_t)(nxt + bk) * HID;
            pw0 = *(const float4*)(wrow + bc); pw1 = *(const float4*)(wrow + bc + 64);
        }
        #pragma unroll
        for (int kk = 0; kk < 16; ++kk) {
            const float4 aA = *(const float4*)&As[cur][kk][ty * 8];
            const float4 aB = *(const float4*)&As[cur][kk][ty * 8 + 4];
            const float4 b0 = *(const float4*)&Bs[cur][kk][tx * 4];
            const float4 b1v = *(const float4*)&Bs[cur][kk][tx * 4 + 64];
            v2f b00; b00[0] = b0.x;  b00[1] = b0.y;
            v2f b01; b01[0] = b0.z;  b01[1] = b0.w;
            v2f b10; b10[0] = b1v.x; b10[1] = b1v.y;
            v2f b11; b11[0] = b1v.z; b11[1] = b1v.w;
            const float arr[8] = {aA.x, aA.y, aA.z, aA.w, aB.x, aB.y, aB.z, aB.w};
            #pragma unroll
            for (int i = 0; i < 8; ++i) {
                v2f ai; ai[0] = arr[i]; ai[1] = arr[i];
                acc[i][0] = __builtin_elementwise_fma(ai, b00, acc[i][0]);
                acc[i][1] = __builtin_elementwise_fma(ai, b01, acc[i][1]);
                acc[i][2] = __builtin_elementwise_fma(ai, b10, acc[i][2]);
                acc[i][3] = __builtin_elementwise_fma(ai, b11, acc[i][3]);
            }
        }
        if (nxt < H2) {
            const int nb = cur ^ 1;
            As[nb][sk + 0][srow] = ph0.x;
            As[nb][sk + 1][srow] = ph0.y;
            As[nb][sk + 2][srow] = ph0.z;
            As[nb][sk + 3][srow] = ph0.w;
            As[nb][sk + 4][srow] = ph1.x;
            As[nb][sk + 5][srow] = ph1.y;
            As[nb][sk + 6][srow] = ph1.z;
            As[nb][sk + 7][srow] = ph1.w;
            *(float4*)&Bs[nb][bk][bc]      = pw0;
            *(float4*)&Bs[nb][bk][bc + 64] = pw1;
            __syncthreads();
        }
        cur ^= 1;
    }
    const int gc = tx * 4;
    float bb[8], iv[8], gg[8], rr[8], ee[8];
    #pragma unroll
    for (int j = 0; j < 8; ++j) {
        int c = (j < 4) ? (gc + j) : (gc + 60 + j);
        bb[j] = b2[c];
        iv[j] = __fdiv_rn(1.0f, __fsqrt_rn(__fadd_rn(rv[c], 1e-5f)));
        gg[j] = g[c];
        rr[j] = rm[c];
        ee[j] = be[c];
    }
    #pragma unroll
    for (int i = 0; i < 8; ++i) {
        const int gr = mbase + ty * 8 + i;
        float cv[8] = {acc[i][0][0], acc[i][0][1], acc[i][1][0], acc[i][1][1],
                       acc[i][2][0], acc[i][2][1], acc[i][3][0], acc[i][3][1]};
        float r[8];
        #pragma unroll
        for (int j = 0; j < 8; ++j) {
            float t = __fadd_rn(cv[j], bb[j]);
            t = __fsub_rn(t, rr[j]); t = __fmul_rn(t, iv[j]);
            t = __fmul_rn(t, gg[j]); t = __fadd_rn(t, ee[j]);
            r[j] = fmaxf(t, 0.f);
        }
        float4 o0; o0.x = r[0]; o0.y = r[1]; o0.z = r[2]; o0.w = r[3];
        float4 o1; o1.x = r[4]; o1.y = r[5]; o1.z = r[6]; o1.w = r[7];
        *(float4*)(Xout + (size_t)gr * HID + gc)      = o0;
        *(float4*)(Xout + (size_t)gr * HID + gc + 64) = o1;
    }
}

// ---------------- per-node projections: y = x.Wrel, z = x.Wroot ----------------
__global__ __launch_bounds__(256) void k_ydot(const float* __restrict__ X,
        const float* __restrict__ Wrel, const float* __restrict__ Wroot,
        float* __restrict__ Y, float* __restrict__ Z) {
    int wave = threadIdx.x >> 6;
    int lane = threadIdx.x & 63;
    int n = blockIdx.x * 4 + wave;
    const float2 xv = *(const float2*)(X + (size_t)n * HID + lane * 2);
    const float2 wr = *(const float2*)(Wrel + lane * 2);
    const float2 wo = *(const float2*)(Wroot + lane * 2);
    float p1 = __fmaf_rn(xv.y, wr.y, __fmul_rn(xv.x, wr.x));
    float p2 = __fmaf_rn(xv.y, wo.y, __fmul_rn(xv.x, wo.x));
    #pragma unroll
    for (int off = 1; off <= 32; off <<= 1) {
        p1 += __shfl_xor(p1, off);
        p2 += __shfl_xor(p2, off);
    }
    if (lane == 0) { Y[n] = p1; Z[n] = p2; }
}

// ---------------- score via scalar gather ----------------
__global__ __launch_bounds__(256) void k_scorelite(const float* __restrict__ Y, const float* __restrict__ Z,
        const int* __restrict__ row_start, const int* __restrict__ csr_src,
        const float* __restrict__ brel, float* __restrict__ S) {
    int n = blockIdx.x * 256 + threadIdx.x;
    int beg = row_start[n], end = row_start[n + 1];
    float p1 = 0.f;
    for (int p = beg; p < end; ++p) p1 = __fadd_rn(p1, Y[csr_src[p]]);
    float pp = __fadd_rn(__fadd_rn(p1, brel[0]), Z[n]);
    const float PC = 7.90531110763549805f;   // XLA fast-tanh input clamp -> plateau tie class
    float s;
    if (pp >= PC)       s = 1.0f;
    else if (pp <= -PC) s = -1.0f;
    else                s = (float)tanh((double)pp);
    S[n] = s;
}

// ---------------- SAGPool top-K + pool + head (fused) ----------------
__global__ __launch_bounds__(512) void k_poolhead(const float* __restrict__ X, const float* __restrict__ S,
        const float* __restrict__ W1, const float* __restrict__ b1,
        const float* __restrict__ gh, const float* __restrict__ beh,
        const float* __restrict__ rmh, const float* __restrict__ rvh,
        const float* __restrict__ W2, const float* __restrict__ b2,
        float* __restrict__ EMB, float* __restrict__ LOGITS) {
    __shared__ unsigned key[512];
    __shared__ double w[512];
    __shared__ double red[4][128];
    __shared__ double embs[128];
    __shared__ double hbuf[128];
    const int b = blockIdx.x, tid = threadIdx.x;
    float v = S[b * NNODE + tid];
    unsigned u = __float_as_uint(v);
    unsigned o = (u & 0x80000000u) ? ~u : (u | 0x80000000u);
    key[tid] = o;
    __syncthreads();
    int rank = 0;
    for (int j = 0; j < NNODE; ++j) {
        unsigned kj = key[j];
        rank += (int)((kj > o) || (kj == o && j < tid));
    }
    w[tid] = (rank < KSEL) ? (double)v : 0.0;
    __syncthreads();
    const int jgrp = tid >> 7;
    const int col = tid & 127;
    double acc = 0.0;
    for (int i = jgrp; i < NNODE; i += 4) {
        acc += (double)X[((size_t)b * NNODE + i) * HID + col] * w[i];
    }
    red[jgrp][col] = acc;
    __syncthreads();
    if (jgrp == 0) {
        double e = red[0][col] + red[1][col] + red[2][col] + red[3][col];
        EMB[b * HID + col] = (float)e;
        embs[col] = e;
    }
    __syncthreads();
    if (tid < 128) {
        double a = 0.0;
        for (int k = 0; k < HID; ++k) a += embs[k] * (double)W1[k * HID + tid];
        a += (double)b1[tid];
        double inv = 1.0 / sqrt((double)rvh[tid] + 1e-5);
        a = (a - (double)rmh[tid]) * inv * (double)gh[tid] + (double)beh[tid];
        hbuf[tid] = fmax(a, 0.0);
    }
    __syncthreads();
    if (tid < OUTC) {
        double a2 = (double)b2[tid];
        for (int k = 0; k < HID; ++k) a2 += hbuf[k] * (double)W2[k * OUTC + tid];
        LOGITS[b * OUTC + tid] = (float)a2;
    }
}

extern "C" void kernel_launch(void* const* d_in, const int* in_sizes, int n_in,
                              void* d_out, int out_size, void* d_ws, size_t ws_size,
                              hipStream_t stream) {
    const float* x     = (const float*)d_in[0];
    const int*   edge  = (const int*)d_in[1];
    const int*   src   = edge;
    const int*   dst   = edge + EDGES;
    const float* epss  = (const float*)d_in[3];
    const float* Ws1   = (const float*)d_in[4];
    const float* bs1   = (const float*)d_in[5];
    const float* g1s   = (const float*)d_in[6];
    const float* be1s  = (const float*)d_in[7];
    const float* rm1s  = (const float*)d_in[8];
    const float* rv1s  = (const float*)d_in[9];
    const float* Ws2   = (const float*)d_in[10];
    const float* bs2   = (const float*)d_in[11];
    const float* gbn   = (const float*)d_in[12];
    const float* bbn   = (const float*)d_in[13];
    const float* rmbn  = (const float*)d_in[14];
    const float* rvbn  = (const float*)d_in[15];
    const float* Wrel  = (const float*)d_in[16];
    const float* brel  = (const float*)d_in[17];
    const float* Wroot = (const float*)d_in[18];
    const float* W_lin1= (const float*)d_in[19];
    const float* b_lin1= (const float*)d_in[20];
    const float* g_h   = (const float*)d_in[21];
    const float* be_h  = (const float*)d_in[22];
    const float* rm_h  = (const float*)d_in[23];
    const float* rv_h  = (const float*)d_in[24];
    const float* W_lin2= (const float*)d_in[25];
    const float* b_lin2= (const float*)d_in[26];

    char* ws = (char*)d_ws;
    float*  x_cur    = (float*) (ws);                    // 32 MB
    float*  xin      = (float*) (ws + 33554432);         // 32 MB
    float*  h1       = (float*) (ws + 67108864);         // 64 MB
    float*  s32      = (float*) (ws + 134217728);        // 256 KB
    float*  ybuf     = (float*) (ws + 134479872);        // 256 KB
    float*  zbuf     = (float*) (ws + 134742016);        // 256 KB
    int*    row_start= (int*)   (ws + 135004160);        // 280 KB (NT_+1 ints)
    int*    csr2     = (int*)   (ws + 135290880);        // 4 MB (edge-order srcs)

    float* emb    = (float*)d_out;
    float* logits = (float*)d_out + BGRAPH * HID;

    // ---- fused per-graph CSR build ----
    k_csr<<<BGRAPH, 512, 0, stream>>>(src, dst, row_start, csr2);

    // ---- layer 0 ----
    k_aggcomb<<<NT_ / 8, 256, 0, stream>>>(x, row_start, csr2, epss, 0, xin);
    k_gemm1<<<1024, 256, 0, stream>>>(xin, Ws1, bs1, g1s, be1s, rm1s, rv1s, 0, h1);
    k_gemm2<<<512, 256, 0, stream>>>(h1, Ws2, bs2, gbn, bbn, rmbn, rvbn, 0, x_cur);
    // ---- layer 1 ----
    k_aggcomb<<<NT_ / 8, 256, 0, stream>>>(x_cur, row_start, csr2, epss, 1, xin);
    k_gemm1<<<1024, 256, 0, stream>>>(xin, Ws1, bs1, g1s, be1s, rm1s, rv1s, 1, h1);
    k_gemm2<<<512, 256, 0, stream>>>(h1, Ws2, bs2, gbn, bbn, rmbn, rvbn, 1, x_cur);
    // ---- scoring via scalar projections, pool+head ----
    k_ydot<<<NT_ / 4, 256, 0, stream>>>(x_cur, Wrel, Wroot, ybuf, zbuf);
    k_scorelite<<<NT_ / 256, 256, 0, stream>>>(ybuf, zbuf, row_start, csr2, brel, s32);
    k_poolhead<<<BGRAPH, 512, 0, stream>>>(x_cur, s32, W_lin1, b_lin1, g_h, be_h, rm_h, rv_h,
                                           W_lin2, b_lin2, emb, logits);
}

// Round 19
// 367.141 us; speedup vs baseline: 1.1038x; 1.0564x over previous
//
#include <hip/hip_runtime.h>
#include <hip/hip_bf16.h>
#include <stdint.h>
#include <math.h>

#define NT_ 65536
#define BGRAPH 128
#define NNODE 512
#define DIM 128
#define HID 128
#define H2 256
#define EDGES 1048576
#define EPG 8192
#define KSEL 256
#define OUTC 10

typedef float v2f __attribute__((ext_vector_type(2)));

// ---------------- fused per-graph CSR build: hist -> scan -> fill -> rank ----------------
__global__ __launch_bounds__(512) void k_csr(const int* __restrict__ src, const int* __restrict__ dst,
                                             int* __restrict__ row_start, int* __restrict__ csr2) {
    __shared__ int hist[512];
    __shared__ int scan_s[512];
    __shared__ int cur[512];
    __shared__ int eids[EPG];
    const int g = blockIdx.x;
    const int t = threadIdx.x;
    const int base = g * EPG;
    const int nb = g * NNODE;
    hist[t] = 0;
    __syncthreads();
    #pragma unroll
    for (int j = t; j < EPG; j += 512) {
        int d = dst[base + j] - nb;
        atomicAdd(&hist[d], 1);
    }
    __syncthreads();
    int v = hist[t];
    scan_s[t] = v;
    __syncthreads();
    for (int off = 1; off < 512; off <<= 1) {
        int u = (t >= off) ? scan_s[t - off] : 0;
        __syncthreads();
        scan_s[t] += u;
        __syncthreads();
    }
    int excl = scan_s[t] - v;
    row_start[nb + t] = base + excl;
    cur[t] = excl;
    if (g == BGRAPH - 1 && t == 511) row_start[NT_] = EDGES;
    __syncthreads();
    #pragma unroll
    for (int j = t; j < EPG; j += 512) {
        int d = dst[base + j] - nb;
        int pos = atomicAdd(&cur[d], 1);
        eids[pos] = (d << 16) | j;
    }
    __syncthreads();
    #pragma unroll
    for (int p = t; p < EPG; p += 512) {
        int packed = eids[p];
        int j = packed & 0xFFFF;
        int d = packed >> 16;
        int beg = scan_s[d] - hist[d];
        int end = scan_s[d];
        int rank = 0;
        for (int q = beg; q < end; ++q) rank += (int)((eids[q] & 0xFFFF) < j);
        csr2[base + beg + rank] = src[base + j];
    }
}

// ---------------- gather + GIN combine: xin = (1+eps)*x + agg ----------------
__global__ __launch_bounds__(256) void k_aggcomb(const float* __restrict__ X,
        const int* __restrict__ row_start, const int* __restrict__ csr_src,
        const float* __restrict__ epss, int l, float* __restrict__ XIN) {
    int bid = blockIdx.x;
    int wg = (bid & 7) * 1024 + (bid >> 3);
    int wave = threadIdx.x >> 6;
    int lane = threadIdx.x & 63;
    int half = lane >> 5;
    int l32 = lane & 31;
    int n = wg * 8 + wave * 2 + half;
    int beg = row_start[n], end = row_start[n + 1];
    const size_t co = (size_t)(l32 * 4);
    const float ep = __fadd_rn(1.0f, epss[l]);
    float a0 = 0.f, a1 = 0.f, a2 = 0.f, a3 = 0.f;
    int p = beg;
    for (; p + 8 <= end; p += 8) {
        int n0 = csr_src[p+0], n1 = csr_src[p+1], n2 = csr_src[p+2], n3 = csr_src[p+3];
        int n4 = csr_src[p+4], n5 = csr_src[p+5], n6 = csr_src[p+6], n7 = csr_src[p+7];
        float4 v0 = *(const float4*)(X + (size_t)n0 * DIM + co);
        float4 v1 = *(const float4*)(X + (size_t)n1 * DIM + co);
        float4 v2 = *(const float4*)(X + (size_t)n2 * DIM + co);
        float4 v3 = *(const float4*)(X + (size_t)n3 * DIM + co);
        float4 v4 = *(const float4*)(X + (size_t)n4 * DIM + co);
        float4 v5 = *(const float4*)(X + (size_t)n5 * DIM + co);
        float4 v6 = *(const float4*)(X + (size_t)n6 * DIM + co);
        float4 v7 = *(const float4*)(X + (size_t)n7 * DIM + co);
        a0 = __fadd_rn(a0, v0.x); a1 = __fadd_rn(a1, v0.y); a2 = __fadd_rn(a2, v0.z); a3 = __fadd_rn(a3, v0.w);
        a0 = __fadd_rn(a0, v1.x); a1 = __fadd_rn(a1, v1.y); a2 = __fadd_rn(a2, v1.z); a3 = __fadd_rn(a3, v1.w);
        a0 = __fadd_rn(a0, v2.x); a1 = __fadd_rn(a1, v2.y); a2 = __fadd_rn(a2, v2.z); a3 = __fadd_rn(a3, v2.w);
        a0 = __fadd_rn(a0, v3.x); a1 = __fadd_rn(a1, v3.y); a2 = __fadd_rn(a2, v3.z); a3 = __fadd_rn(a3, v3.w);
        a0 = __fadd_rn(a0, v4.x); a1 = __fadd_rn(a1, v4.y); a2 = __fadd_rn(a2, v4.z); a3 = __fadd_rn(a3, v4.w);
        a0 = __fadd_rn(a0, v5.x); a1 = __fadd_rn(a1, v5.y); a2 = __fadd_rn(a2, v5.z); a3 = __fadd_rn(a3, v5.w);
        a0 = __fadd_rn(a0, v6.x); a1 = __fadd_rn(a1, v6.y); a2 = __fadd_rn(a2, v6.z); a3 = __fadd_rn(a3, v6.w);
        a0 = __fadd_rn(a0, v7.x); a1 = __fadd_rn(a1, v7.y); a2 = __fadd_rn(a2, v7.z); a3 = __fadd_rn(a3, v7.w);
    }
    for (; p < end; ++p) {
        int nbr = csr_src[p];
        float4 v = *(const float4*)(X + (size_t)nbr * DIM + co);
        a0 = __fadd_rn(a0, v.x); a1 = __fadd_rn(a1, v.y); a2 = __fadd_rn(a2, v.z); a3 = __fadd_rn(a3, v.w);
    }
    float4 xv = *(const float4*)(X + (size_t)n * DIM + co);
    float4 o;
    o.x = __fadd_rn(__fmul_rn(ep, xv.x), a0);
    o.y = __fadd_rn(__fmul_rn(ep, xv.y), a1);
    o.z = __fadd_rn(__fmul_rn(ep, xv.z), a2);
    o.w = __fadd_rn(__fmul_rn(ep, xv.w), a3);
    *(float4*)(XIN + (size_t)n * DIM + co) = o;
}

// ---------------- GEMM1: h1 = relu(bn(XIN @ W1 + b1)), 128x128 tile, BK=16, dbuf ----------------
__global__ __launch_bounds__(256) void k_gemm1(const float* __restrict__ XIN,
        const float* __restrict__ Ws1, const float* __restrict__ bs1,
        const float* __restrict__ g1s, const float* __restrict__ be1s, const float* __restrict__ rm1s,
        const float* __restrict__ rv1s, int l, float* __restrict__ H1out) {
    __shared__ float As[2][16][132];
    __shared__ float Bs[2][16][132];
    const float* W1  = Ws1 + (size_t)l * DIM * H2;
    const float* b1  = bs1 + l * H2;
    const float* g1  = g1s + l * H2;
    const float* be1 = be1s + l * H2;
    const float* rm1 = rm1s + l * H2;
    const float* rv1 = rv1s + l * H2;
    int bid = blockIdx.x;
    int wg = (bid & 7) * 128 + (bid >> 3);
    const int mbase = (wg >> 1) * 128;
    const int nbase = (wg & 1) * 128;
    const int tid = threadIdx.x;
    const int srow = tid >> 1;
    const int sk   = (tid & 1) * 8;
    const int bk   = tid >> 4;
    const int bc   = (tid & 15) * 4;
    const int ty = tid >> 4;
    const int tx = tid & 15;
    v2f acc[8][4] = {};
    const float* xr = XIN + (size_t)(mbase + srow) * DIM + sk;
    float4 px0, px1, pw0, pw1;
    px0 = *(const float4*)(xr);     px1 = *(const float4*)(xr + 4);
    {
        const float* wrow = W1 + (size_t)bk * H2 + nbase;
        pw0 = *(const float4*)(wrow + bc); pw1 = *(const float4*)(wrow + bc + 64);
    }
    As[0][sk + 0][srow] = px0.x;
    As[0][sk + 1][srow] = px0.y;
    As[0][sk + 2][srow] = px0.z;
    As[0][sk + 3][srow] = px0.w;
    As[0][sk + 4][srow] = px1.x;
    As[0][sk + 5][srow] = px1.y;
    As[0][sk + 6][srow] = px1.z;
    As[0][sk + 7][srow] = px1.w;
    *(float4*)&Bs[0][bk][bc]      = pw0;
    *(float4*)&Bs[0][bk][bc + 64] = pw1;
    __syncthreads();
    int cur = 0;
    for (int kt = 0; kt < DIM; kt += 16) {
        const int nxt = kt + 16;
        if (nxt < DIM) {
            px0 = *(const float4*)(xr + nxt);     px1 = *(const float4*)(xr + nxt + 4);
            const float* wrow = W1 + (size_t)(nxt + bk) * H2 + nbase;
            pw0 = *(const float4*)(wrow + bc); pw1 = *(const float4*)(wrow + bc + 64);
        }
        #pragma unroll
        for (int kk = 0; kk < 16; ++kk) {
            const float4 aA = *(const float4*)&As[cur][kk][ty * 8];
            const float4 aB = *(const float4*)&As[cur][kk][ty * 8 + 4];
            const float4 b0 = *(const float4*)&Bs[cur][kk][tx * 4];
            const float4 b1v = *(const float4*)&Bs[cur][kk][tx * 4 + 64];
            v2f b00; b00[0] = b0.x;  b00[1] = b0.y;
            v2f b01; b01[0] = b0.z;  b01[1] = b0.w;
            v2f b10; b10[0] = b1v.x; b10[1] = b1v.y;
            v2f b11; b11[0] = b1v.z; b11[1] = b1v.w;
            const float arr[8] = {aA.x, aA.y, aA.z, aA.w, aB.x, aB.y, aB.z, aB.w};
            #pragma unroll
            for (int i = 0; i < 8; ++i) {
                v2f ai; ai[0] = arr[i]; ai[1] = arr[i];
                acc[i][0] = __builtin_elementwise_fma(ai, b00, acc[i][0]);
                acc[i][1] = __builtin_elementwise_fma(ai, b01, acc[i][1]);
                acc[i][2] = __builtin_elementwise_fma(ai, b10, acc[i][2]);
                acc[i][3] = __builtin_elementwise_fma(ai, b11, acc[i][3]);
            }
        }
        if (nxt < DIM) {
            const int nb = cur ^ 1;
            As[nb][sk + 0][srow] = px0.x;
            As[nb][sk + 1][srow] = px0.y;
            As[nb][sk + 2][srow] = px0.z;
            As[nb][sk + 3][srow] = px0.w;
            As[nb][sk + 4][srow] = px1.x;
            As[nb][sk + 5][srow] = px1.y;
            As[nb][sk + 6][srow] = px1.z;
            As[nb][sk + 7][srow] = px1.w;
            *(float4*)&Bs[nb][bk][bc]      = pw0;
            *(float4*)&Bs[nb][bk][bc + 64] = pw1;
            __syncthreads();
        }
        cur ^= 1;
    }
    const int gc = nbase + tx * 4;
    float bb[8], iv[8], gg[8], rr[8], ee[8];
    #pragma unroll
    for (int j = 0; j < 8; ++j) {
        int c = (j < 4) ? (gc + j) : (gc + 60 + j);
        bb[j] = b1[c];
        iv[j] = __fdiv_rn(1.0f, __fsqrt_rn(__fadd_rn(rv1[c], 1e-5f)));
        gg[j] = g1[c];
        rr[j] = rm1[c];
        ee[j] = be1[c];
    }
    #pragma unroll
    for (int i = 0; i < 8; ++i) {
        const int gr = mbase + ty * 8 + i;
        float cv[8] = {acc[i][0][0], acc[i][0][1], acc[i][1][0], acc[i][1][1],
                       acc[i][2][0], acc[i][2][1], acc[i][3][0], acc[i][3][1]};
        float r[8];
        #pragma unroll
        for (int j = 0; j < 8; ++j) {
            float t = __fadd_rn(cv[j], bb[j]);
            t = __fsub_rn(t, rr[j]); t = __fmul_rn(t, iv[j]);
            t = __fmul_rn(t, gg[j]); t = __fadd_rn(t, ee[j]);
            r[j] = fmaxf(t, 0.f);
        }
        float4 o0; o0.x = r[0]; o0.y = r[1]; o0.z = r[2]; o0.w = r[3];
        float4 o1; o1.x = r[4]; o1.y = r[5]; o1.z = r[6]; o1.w = r[7];
        *(float4*)(H1out + (size_t)gr * H2 + gc)      = o0;
        *(float4*)(H1out + (size_t)gr * H2 + gc + 64) = o1;
    }
}

// ---------------- GEMM2: 128x128 tile, BK=16, dbuf ping-pong ----------------
__global__ __launch_bounds__(256) void k_gemm2(const float* __restrict__ H1, const float* __restrict__ Ws2,
        const float* __restrict__ bs2, const float* __restrict__ gbn, const float* __restrict__ bbn,
        const float* __restrict__ rmbn, const float* __restrict__ rvbn, int l, float* __restrict__ Xout) {
    __shared__ float As[2][16][132];
    __shared__ float Bs[2][16][132];
    const float* W2 = Ws2 + (size_t)l * H2 * HID;
    const float* b2 = bs2 + l * HID;
    const float* g  = gbn + l * HID;
    const float* be = bbn + l * HID;
    const float* rm = rmbn + l * HID;
    const float* rv = rvbn + l * HID;
    int bid = blockIdx.x;
    int wg = (bid & 7) * 64 + (bid >> 3);
    const int mbase = wg * 128;
    const int tid = threadIdx.x;
    const int srow = tid >> 1;
    const int sk   = (tid & 1) * 8;
    const int bk   = tid >> 4;
    const int bc   = (tid & 15) * 4;
    const int ty = tid >> 4;
    const int tx = tid & 15;
    v2f acc[8][4] = {};
    const float* hr = H1 + (size_t)(mbase + srow) * H2 + sk;
    float4 ph0, ph1, pw0, pw1;
    ph0 = *(const float4*)(hr);     ph1 = *(const float4*)(hr + 4);
    {
        const float* wrow = W2 + (size_t)bk * HID;
        pw0 = *(const float4*)(wrow + bc); pw1 = *(const float4*)(wrow + bc + 64);
    }
    As[0][sk + 0][srow] = ph0.x;
    As[0][sk + 1][srow] = ph0.y;
    As[0][sk + 2][srow] = ph0.z;
    As[0][sk + 3][srow] = ph0.w;
    As[0][sk + 4][srow] = ph1.x;
    As[0][sk + 5][srow] = ph1.y;
    As[0][sk + 6][srow] = ph1.z;
    As[0][sk + 7][srow] = ph1.w;
    *(float4*)&Bs[0][bk][bc]      = pw0;
    *(float4*)&Bs[0][bk][bc + 64] = pw1;
    __syncthreads();
    int cur = 0;
    for (int kt = 0; kt < H2; kt += 16) {
        const int nxt = kt + 16;
        if (nxt < H2) {
            ph0 = *(const float4*)(hr + nxt);     ph1 = *(const float4*)(hr + nxt + 4);
            const float* wrow = W2 + (size_t)(nxt + bk) * HID;
            pw0 = *(const float4*)(wrow + bc); pw1 = *(const float4*)(wrow + bc + 64);
        }
        #pragma unroll
        for (int kk = 0; kk < 16; ++kk) {
            const float4 aA = *(const float4*)&As[cur][kk][ty * 8];
            const float4 aB = *(const float4*)&As[cur][kk][ty * 8 + 4];
            const float4 b0 = *(const float4*)&Bs[cur][kk][tx * 4];
            const float4 b1v = *(const float4*)&Bs[cur][kk][tx * 4 + 64];
            v2f b00; b00[0] = b0.x;  b00[1] = b0.y;
            v2f b01; b01[0] = b0.z;  b01[1] = b0.w;
            v2f b10; b10[0] = b1v.x; b10[1] = b1v.y;
            v2f b11; b11[0] = b1v.z; b11[1] = b1v.w;
            const float arr[8] = {aA.x, aA.y, aA.z, aA.w, aB.x, aB.y, aB.z, aB.w};
            #pragma unroll
            for (int i = 0; i < 8; ++i) {
                v2f ai; ai[0] = arr[i]; ai[1] = arr[i];
                acc[i][0] = __builtin_elementwise_fma(ai, b00, acc[i][0]);
                acc[i][1] = __builtin_elementwise_fma(ai, b01, acc[i][1]);
                acc[i][2] = __builtin_elementwise_fma(ai, b10, acc[i][2]);
                acc[i][3] = __builtin_elementwise_fma(ai, b11, acc[i][3]);
            }
        }
        if (nxt < H2) {
            const int nb = cur ^ 1;
            As[nb][sk + 0][srow] = ph0.x;
            As[nb][sk + 1][srow] = ph0.y;
            As[nb][sk + 2][srow] = ph0.z;
            As[nb][sk + 3][srow] = ph0.w;
            As[nb][sk + 4][srow] = ph1.x;
            As[nb][sk + 5][srow] = ph1.y;
            As[nb][sk + 6][srow] = ph1.z;
            As[nb][sk + 7][srow] = ph1.w;
            *(float4*)&Bs[nb][bk][bc]      = pw0;
            *(float4*)&Bs[nb][bk][bc + 64] = pw1;
            __syncthreads();
        }
        cur ^= 1;
    }
    const int gc = tx * 4;
    float bb[8], iv[8], gg[8], rr[8], ee[8];
    #pragma unroll
    for (int j = 0; j < 8; ++j) {
        int c = (j < 4) ? (gc + j) : (gc + 60 + j);
        bb[j] = b2[c];
        iv[j] = __fdiv_rn(1.0f, __fsqrt_rn(__fadd_rn(rv[c], 1e-5f)));
        gg[j] = g[c];
        rr[j] = rm[c];
        ee[j] = be[c];
    }
    #pragma unroll
    for (int i = 0; i < 8; ++i) {
        const int gr = mbase + ty * 8 + i;
        float cv[8] = {acc[i][0][0], acc[i][0][1], acc[i][1][0], acc[i][1][1],
                       acc[i][2][0], acc[i][2][1], acc[i][3][0], acc[i][3][1]};
        float r[8];
        #pragma unroll
        for (int j = 0; j < 8; ++j) {
            float t = __fadd_rn(cv[j], bb[j]);
            t = __fsub_rn(t, rr[j]); t = __fmul_rn(t, iv[j]);
            t = __fmul_rn(t, gg[j]); t = __fadd_rn(t, ee[j]);
            r[j] = fmaxf(t, 0.f);
        }
        float4 o0; o0.x = r[0]; o0.y = r[1]; o0.z = r[2]; o0.w = r[3];
        float4 o1; o1.x = r[4]; o1.y = r[5]; o1.z = r[6]; o1.w = r[7];
        *(float4*)(Xout + (size_t)gr * HID + gc)      = o0;
        *(float4*)(Xout + (size_t)gr * HID + gc + 64) = o1;
    }
}

// ---------------- per-node projections: y = x.Wrel, z = x.Wroot ----------------
__global__ __launch_bounds__(256) void k_ydot(const float* __restrict__ X,
        const float* __restrict__ Wrel, const float* __restrict__ Wroot,
        float* __restrict__ Y, float* __restrict__ Z) {
    int wave = threadIdx.x >> 6;
    int lane = threadIdx.x & 63;
    int n = blockIdx.x * 4 + wave;
    const float2 xv = *(const float2*)(X + (size_t)n * HID + lane * 2);
    const float2 wr = *(const float2*)(Wrel + lane * 2);
    const float2 wo = *(const float2*)(Wroot + lane * 2);
    float p1 = __fmaf_rn(xv.y, wr.y, __fmul_rn(xv.x, wr.x));
    float p2 = __fmaf_rn(xv.y, wo.y, __fmul_rn(xv.x, wo.x));
    #pragma unroll
    for (int off = 1; off <= 32; off <<= 1) {
        p1 += __shfl_xor(p1, off);
        p2 += __shfl_xor(p2, off);
    }
    if (lane == 0) { Y[n] = p1; Z[n] = p2; }
}

// ---------------- fused score + top-K selection: wsel[n] = selected ? s : 0 ----------------
__global__ __launch_bounds__(512) void k_selscore(const float* __restrict__ Y, const float* __restrict__ Z,
        const int* __restrict__ row_start, const int* __restrict__ csr_src,
        const float* __restrict__ brel, float* __restrict__ WSEL) {
    __shared__ unsigned key[512];
    const int b = blockIdx.x, t = threadIdx.x;
    const int n = b * NNODE + t;
    int beg = row_start[n], end = row_start[n + 1];
    float p1 = 0.f;
    for (int p = beg; p < end; ++p) p1 = __fadd_rn(p1, Y[csr_src[p]]);
    float pp = __fadd_rn(__fadd_rn(p1, brel[0]), Z[n]);
    const float PC = 7.90531110763549805f;   // XLA fast-tanh input clamp -> plateau tie class
    float s;
    if (pp >= PC)       s = 1.0f;
    else if (pp <= -PC) s = -1.0f;
    else                s = (float)tanh((double)pp);
    unsigned u = __float_as_uint(s);
    unsigned o = (u & 0x80000000u) ? ~u : (u | 0x80000000u);
    key[t] = o;
    __syncthreads();
    int rank = 0;
    for (int j = 0; j < NNODE; ++j) {
        unsigned kj = key[j];
        rank += (int)((kj > o) || (kj == o && j < t));
    }
    WSEL[n] = (rank < KSEL) ? s : 0.0f;
}

// ---------------- weighted partial sums: 4 blocks/graph x 2 halves ----------------
__global__ __launch_bounds__(256) void k_wsum(const float* __restrict__ X,
        const float* __restrict__ WSEL, double* __restrict__ PB) {
    __shared__ float wl[128];
    const int blk = blockIdx.x;          // g*4 + q
    const int g = blk >> 2, q = blk & 3;
    const int t = threadIdx.x;
    const int col = t & 127, half = t >> 7;
    if (t < 128) wl[t] = WSEL[g * NNODE + q * 128 + t];
    __syncthreads();
    const int lr0 = half * 64;           // local row base within quarter
    const float* xb = X + ((size_t)(g * NNODE + q * 128 + lr0)) * HID + col;
    double acc = 0.0;
    #pragma unroll 4
    for (int i = 0; i < 64; ++i) {
        acc += (double)xb[(size_t)i * HID] * (double)wl[lr0 + i];
    }
    PB[((size_t)blk * 2 + half) * 128 + col] = acc;
}

// ---------------- combine partials + head ----------------
__global__ __launch_bounds__(128) void k_headc(const double* __restrict__ PB,
        const float* __restrict__ W1, const float* __restrict__ b1,
        const float* __restrict__ gh, const float* __restrict__ beh,
        const float* __restrict__ rmh, const float* __restrict__ rvh,
        const float* __restrict__ W2, const float* __restrict__ b2,
        float* __restrict__ EMB, float* __restrict__ LOGITS) {
    __shared__ double embs[128];
    __shared__ double hbuf[128];
    const int b = blockIdx.x, t = threadIdx.x;
    double e = 0.0;
    #pragma unroll
    for (int part = 0; part < 8; ++part) {       // q*2+half ascending
        e += PB[((size_t)(b * 4) * 2 + part) * 128 + t];
    }
    EMB[b * HID + t] = (float)e;
    embs[t] = e;
    __syncthreads();
    double a = 0.0;
    for (int k = 0; k < HID; ++k) a += embs[k] * (double)W1[k * HID + t];
    a += (double)b1[t];
    double inv = 1.0 / sqrt((double)rvh[t] + 1e-5);
    a = (a - (double)rmh[t]) * inv * (double)gh[t] + (double)beh[t];
    hbuf[t] = fmax(a, 0.0);
    __syncthreads();
    if (t < OUTC) {
        double a2 = (double)b2[t];
        for (int k = 0; k < HID; ++k) a2 += hbuf[k] * (double)W2[k * OUTC + t];
        LOGITS[b * OUTC + t] = (float)a2;
    }
}

extern "C" void kernel_launch(void* const* d_in, const int* in_sizes, int n_in,
                              void* d_out, int out_size, void* d_ws, size_t ws_size,
                              hipStream_t stream) {
    const float* x     = (const float*)d_in[0];
    const int*   edge  = (const int*)d_in[1];
    const int*   src   = edge;
    const int*   dst   = edge + EDGES;
    const float* epss  = (const float*)d_in[3];
    const float* Ws1   = (const float*)d_in[4];
    const float* bs1   = (const float*)d_in[5];
    const float* g1s   = (const float*)d_in[6];
    const float* be1s  = (const float*)d_in[7];
    const float* rm1s  = (const float*)d_in[8];
    const float* rv1s  = (const float*)d_in[9];
    const float* Ws2   = (const float*)d_in[10];
    const float* bs2   = (const float*)d_in[11];
    const float* gbn   = (const float*)d_in[12];
    const float* bbn   = (const float*)d_in[13];
    const float* rmbn  = (const float*)d_in[14];
    const float* rvbn  = (const float*)d_in[15];
    const float* Wrel  = (const float*)d_in[16];
    const float* brel  = (const float*)d_in[17];
    const float* Wroot = (const float*)d_in[18];
    const float* W_lin1= (const float*)d_in[19];
    const float* b_lin1= (const float*)d_in[20];
    const float* g_h   = (const float*)d_in[21];
    const float* be_h  = (const float*)d_in[22];
    const float* rm_h  = (const float*)d_in[23];
    const float* rv_h  = (const float*)d_in[24];
    const float* W_lin2= (const float*)d_in[25];
    const float* b_lin2= (const float*)d_in[26];

    char* ws = (char*)d_ws;
    float*  x_cur    = (float*) (ws);                    // 32 MB
    float*  xin      = (float*) (ws + 33554432);         // 32 MB
    float*  h1       = (float*) (ws + 67108864);         // 64 MB
    float*  wsel     = (float*) (ws + 134217728);        // 256 KB
    float*  ybuf     = (float*) (ws + 134479872);        // 256 KB
    float*  zbuf     = (float*) (ws + 134742016);        // 256 KB
    double* pbuf     = (double*)(ws + 135004160);        // 1 MB (1024 x 128 doubles)
    int*    row_start= (int*)   (ws + 136052736);        // 280 KB (NT_+1 ints)
    int*    csr2     = (int*)   (ws + 136339456);        // 4 MB (edge-order srcs)

    float* emb    = (float*)d_out;
    float* logits = (float*)d_out + BGRAPH * HID;

    // ---- fused per-graph CSR build ----
    k_csr<<<BGRAPH, 512, 0, stream>>>(src, dst, row_start, csr2);

    // ---- layer 0 ----
    k_aggcomb<<<NT_ / 8, 256, 0, stream>>>(x, row_start, csr2, epss, 0, xin);
    k_gemm1<<<1024, 256, 0, stream>>>(xin, Ws1, bs1, g1s, be1s, rm1s, rv1s, 0, h1);
    k_gemm2<<<512, 256, 0, stream>>>(h1, Ws2, bs2, gbn, bbn, rmbn, rvbn, 0, x_cur);
    // ---- layer 1 ----
    k_aggcomb<<<NT_ / 8, 256, 0, stream>>>(x_cur, row_start, csr2, epss, 1, xin);
    k_gemm1<<<1024, 256, 0, stream>>>(xin, Ws1, bs1, g1s, be1s, rm1s, rv1s, 1, h1);
    k_gemm2<<<512, 256, 0, stream>>>(h1, Ws2, bs2, gbn, bbn, rmbn, rvbn, 1, x_cur);
    // ---- scoring + selection + pool + head ----
    k_ydot<<<NT_ / 4, 256, 0, stream>>>(x_cur, Wrel, Wroot, ybuf, zbuf);
    k_selscore<<<BGRAPH, 512, 0, stream>>>(ybuf, zbuf, row_start, csr2, brel, wsel);
    k_wsum<<<4 * BGRAPH, 256, 0, stream>>>(x_cur, wsel, pbuf);
    k_headc<<<BGRAPH, 128, 0, stream>>>(pbuf, W_lin1, b_lin1, g_h, be_h, rm_h, rv_h,
                                        W_lin2, b_lin2, emb, logits);
}

// Round 20
// 359.308 us; speedup vs baseline: 1.1279x; 1.0218x over previous
//
#include <hip/hip_runtime.h>
#include <hip/hip_bf16.h>
#include <stdint.h>
#include <math.h>

#define NT_ 65536
#define BGRAPH 128
#define NNODE 512
#define DIM 128
#define HID 128
#define H2 256
#define EDGES 1048576
#define EPG 8192
#define KSEL 256
#define OUTC 10

typedef float v2f __attribute__((ext_vector_type(2)));

// ---------------- fused per-graph CSR build: hist -> scan -> fill -> rank ----------------
__global__ __launch_bounds__(512) void k_csr(const int* __restrict__ src, const int* __restrict__ dst,
                                             int* __restrict__ row_start, int* __restrict__ csr2) {
    __shared__ int hist[512];
    __shared__ int scan_s[512];
    __shared__ int cur[512];
    __shared__ int eids[EPG];
    const int g = blockIdx.x;
    const int t = threadIdx.x;
    const int base = g * EPG;
    const int nb = g * NNODE;
    hist[t] = 0;
    __syncthreads();
    #pragma unroll
    for (int j = t; j < EPG; j += 512) {
        int d = dst[base + j] - nb;
        atomicAdd(&hist[d], 1);
    }
    __syncthreads();
    int v = hist[t];
    scan_s[t] = v;
    __syncthreads();
    for (int off = 1; off < 512; off <<= 1) {
        int u = (t >= off) ? scan_s[t - off] : 0;
        __syncthreads();
        scan_s[t] += u;
        __syncthreads();
    }
    int excl = scan_s[t] - v;
    row_start[nb + t] = base + excl;
    cur[t] = excl;
    if (g == BGRAPH - 1 && t == 511) row_start[NT_] = EDGES;
    __syncthreads();
    #pragma unroll
    for (int j = t; j < EPG; j += 512) {
        int d = dst[base + j] - nb;
        int pos = atomicAdd(&cur[d], 1);
        eids[pos] = (d << 16) | j;
    }
    __syncthreads();
    #pragma unroll
    for (int p = t; p < EPG; p += 512) {
        int packed = eids[p];
        int j = packed & 0xFFFF;
        int d = packed >> 16;
        int beg = scan_s[d] - hist[d];
        int end = scan_s[d];
        int rank = 0;
        for (int q = beg; q < end; ++q) rank += (int)((eids[q] & 0xFFFF) < j);
        csr2[base + beg + rank] = src[base + j];
    }
}

// ---------------- gather + GIN combine: xin = (1+eps)*x + agg ----------------
__global__ __launch_bounds__(256) void k_aggcomb(const float* __restrict__ X,
        const int* __restrict__ row_start, const int* __restrict__ csr_src,
        const float* __restrict__ epss, int l, float* __restrict__ XIN) {
    int bid = blockIdx.x;
    int wg = (bid & 7) * 1024 + (bid >> 3);
    int wave = threadIdx.x >> 6;
    int lane = threadIdx.x & 63;
    int half = lane >> 5;
    int l32 = lane & 31;
    int n = wg * 8 + wave * 2 + half;
    int beg = row_start[n], end = row_start[n + 1];
    const size_t co = (size_t)(l32 * 4);
    const float ep = __fadd_rn(1.0f, epss[l]);
    float a0 = 0.f, a1 = 0.f, a2 = 0.f, a3 = 0.f;
    int p = beg;
    for (; p + 8 <= end; p += 8) {
        int n0 = csr_src[p+0], n1 = csr_src[p+1], n2 = csr_src[p+2], n3 = csr_src[p+3];
        int n4 = csr_src[p+4], n5 = csr_src[p+5], n6 = csr_src[p+6], n7 = csr_src[p+7];
        float4 v0 = *(const float4*)(X + (size_t)n0 * DIM + co);
        float4 v1 = *(const float4*)(X + (size_t)n1 * DIM + co);
        float4 v2 = *(const float4*)(X + (size_t)n2 * DIM + co);
        float4 v3 = *(const float4*)(X + (size_t)n3 * DIM + co);
        float4 v4 = *(const float4*)(X + (size_t)n4 * DIM + co);
        float4 v5 = *(const float4*)(X + (size_t)n5 * DIM + co);
        float4 v6 = *(const float4*)(X + (size_t)n6 * DIM + co);
        float4 v7 = *(const float4*)(X + (size_t)n7 * DIM + co);
        a0 = __fadd_rn(a0, v0.x); a1 = __fadd_rn(a1, v0.y); a2 = __fadd_rn(a2, v0.z); a3 = __fadd_rn(a3, v0.w);
        a0 = __fadd_rn(a0, v1.x); a1 = __fadd_rn(a1, v1.y); a2 = __fadd_rn(a2, v1.z); a3 = __fadd_rn(a3, v1.w);
        a0 = __fadd_rn(a0, v2.x); a1 = __fadd_rn(a1, v2.y); a2 = __fadd_rn(a2, v2.z); a3 = __fadd_rn(a3, v2.w);
        a0 = __fadd_rn(a0, v3.x); a1 = __fadd_rn(a1, v3.y); a2 = __fadd_rn(a2, v3.z); a3 = __fadd_rn(a3, v3.w);
        a0 = __fadd_rn(a0, v4.x); a1 = __fadd_rn(a1, v4.y); a2 = __fadd_rn(a2, v4.z); a3 = __fadd_rn(a3, v4.w);
        a0 = __fadd_rn(a0, v5.x); a1 = __fadd_rn(a1, v5.y); a2 = __fadd_rn(a2, v5.z); a3 = __fadd_rn(a3, v5.w);
        a0 = __fadd_rn(a0, v6.x); a1 = __fadd_rn(a1, v6.y); a2 = __fadd_rn(a2, v6.z); a3 = __fadd_rn(a3, v6.w);
        a0 = __fadd_rn(a0, v7.x); a1 = __fadd_rn(a1, v7.y); a2 = __fadd_rn(a2, v7.z); a3 = __fadd_rn(a3, v7.w);
    }
    for (; p < end; ++p) {
        int nbr = csr_src[p];
        float4 v = *(const float4*)(X + (size_t)nbr * DIM + co);
        a0 = __fadd_rn(a0, v.x); a1 = __fadd_rn(a1, v.y); a2 = __fadd_rn(a2, v.z); a3 = __fadd_rn(a3, v.w);
    }
    float4 xv = *(const float4*)(X + (size_t)n * DIM + co);
    float4 o;
    o.x = __fadd_rn(__fmul_rn(ep, xv.x), a0);
    o.y = __fadd_rn(__fmul_rn(ep, xv.y), a1);
    o.z = __fadd_rn(__fmul_rn(ep, xv.z), a2);
    o.w = __fadd_rn(__fmul_rn(ep, xv.w), a3);
    *(float4*)(XIN + (size_t)n * DIM + co) = o;
}

// ---------------- GEMM1: h1 = relu(bn(XIN @ W1 + b1)), 128x128 tile, BK=16, dbuf ----------------
__global__ __launch_bounds__(256) void k_gemm1(const float* __restrict__ XIN,
        const float* __restrict__ Ws1, const float* __restrict__ bs1,
        const float* __restrict__ g1s, const float* __restrict__ be1s, const float* __restrict__ rm1s,
        const float* __restrict__ rv1s, int l, float* __restrict__ H1out) {
    __shared__ float As[2][16][132];
    __shared__ float Bs[2][16][132];
    const float* W1  = Ws1 + (size_t)l * DIM * H2;
    const float* b1  = bs1 + l * H2;
    const float* g1  = g1s + l * H2;
    const float* be1 = be1s + l * H2;
    const float* rm1 = rm1s + l * H2;
    const float* rv1 = rv1s + l * H2;
    int bid = blockIdx.x;
    int wg = (bid & 7) * 128 + (bid >> 3);
    const int mbase = (wg >> 1) * 128;
    const int nbase = (wg & 1) * 128;
    const int tid = threadIdx.x;
    const int srow = tid >> 1;
    const int sk   = (tid & 1) * 8;
    const int bk   = tid >> 4;
    const int bc   = (tid & 15) * 4;
    const int ty = tid >> 4;
    const int tx = tid & 15;
    v2f acc[8][4] = {};
    const float* xr = XIN + (size_t)(mbase + srow) * DIM + sk;
    float4 px0, px1, pw0, pw1;
    px0 = *(const float4*)(xr);     px1 = *(const float4*)(xr + 4);
    {
        const float* wrow = W1 + (size_t)bk * H2 + nbase;
        pw0 = *(const float4*)(wrow + bc); pw1 = *(const float4*)(wrow + bc + 64);
    }
    As[0][sk + 0][srow] = px0.x;
    As[0][sk + 1][srow] = px0.y;
    As[0][sk + 2][srow] = px0.z;
    As[0][sk + 3][srow] = px0.w;
    As[0][sk + 4][srow] = px1.x;
    As[0][sk + 5][srow] = px1.y;
    As[0][sk + 6][srow] = px1.z;
    As[0][sk + 7][srow] = px1.w;
    *(float4*)&Bs[0][bk][bc]      = pw0;
    *(float4*)&Bs[0][bk][bc + 64] = pw1;
    __syncthreads();
    int cur = 0;
    for (int kt = 0; kt < DIM; kt += 16) {
        const int nxt = kt + 16;
        if (nxt < DIM) {
            px0 = *(const float4*)(xr + nxt);     px1 = *(const float4*)(xr + nxt + 4);
            const float* wrow = W1 + (size_t)(nxt + bk) * H2 + nbase;
            pw0 = *(const float4*)(wrow + bc); pw1 = *(const float4*)(wrow + bc + 64);
        }
        #pragma unroll
        for (int kk = 0; kk < 16; ++kk) {
            const float4 aA = *(const float4*)&As[cur][kk][ty * 8];
            const float4 aB = *(const float4*)&As[cur][kk][ty * 8 + 4];
            const float4 b0 = *(const float4*)&Bs[cur][kk][tx * 4];
            const float4 b1v = *(const float4*)&Bs[cur][kk][tx * 4 + 64];
            v2f b00; b00[0] = b0.x;  b00[1] = b0.y;
            v2f b01; b01[0] = b0.z;  b01[1] = b0.w;
            v2f b10; b10[0] = b1v.x; b10[1] = b1v.y;
            v2f b11; b11[0] = b1v.z; b11[1] = b1v.w;
            const float arr[8] = {aA.x, aA.y, aA.z, aA.w, aB.x, aB.y, aB.z, aB.w};
            #pragma unroll
            for (int i = 0; i < 8; ++i) {
                v2f ai; ai[0] = arr[i]; ai[1] = arr[i];
                acc[i][0] = __builtin_elementwise_fma(ai, b00, acc[i][0]);
                acc[i][1] = __builtin_elementwise_fma(ai, b01, acc[i][1]);
                acc[i][2] = __builtin_elementwise_fma(ai, b10, acc[i][2]);
                acc[i][3] = __builtin_elementwise_fma(ai, b11, acc[i][3]);
            }
        }
        if (nxt < DIM) {
            const int nb = cur ^ 1;
            As[nb][sk + 0][srow] = px0.x;
            As[nb][sk + 1][srow] = px0.y;
            As[nb][sk + 2][srow] = px0.z;
            As[nb][sk + 3][srow] = px0.w;
            As[nb][sk + 4][srow] = px1.x;
            As[nb][sk + 5][srow] = px1.y;
            As[nb][sk + 6][srow] = px1.z;
            As[nb][sk + 7][srow] = px1.w;
            *(float4*)&Bs[nb][bk][bc]      = pw0;
            *(float4*)&Bs[nb][bk][bc + 64] = pw1;
            __syncthreads();
        }
        cur ^= 1;
    }
    const int gc = nbase + tx * 4;
    float bb[8], iv[8], gg[8], rr[8], ee[8];
    #pragma unroll
    for (int j = 0; j < 8; ++j) {
        int c = (j < 4) ? (gc + j) : (gc + 60 + j);
        bb[j] = b1[c];
        iv[j] = __fdiv_rn(1.0f, __fsqrt_rn(__fadd_rn(rv1[c], 1e-5f)));
        gg[j] = g1[c];
        rr[j] = rm1[c];
        ee[j] = be1[c];
    }
    #pragma unroll
    for (int i = 0; i < 8; ++i) {
        const int gr = mbase + ty * 8 + i;
        float cv[8] = {acc[i][0][0], acc[i][0][1], acc[i][1][0], acc[i][1][1],
                       acc[i][2][0], acc[i][2][1], acc[i][3][0], acc[i][3][1]};
        float r[8];
        #pragma unroll
        for (int j = 0; j < 8; ++j) {
            float t = __fadd_rn(cv[j], bb[j]);
            t = __fsub_rn(t, rr[j]); t = __fmul_rn(t, iv[j]);
            t = __fmul_rn(t, gg[j]); t = __fadd_rn(t, ee[j]);
            r[j] = fmaxf(t, 0.f);
        }
        float4 o0; o0.x = r[0]; o0.y = r[1]; o0.z = r[2]; o0.w = r[3];
        float4 o1; o1.x = r[4]; o1.y = r[5]; o1.z = r[6]; o1.w = r[7];
        *(float4*)(H1out + (size_t)gr * H2 + gc)      = o0;
        *(float4*)(H1out + (size_t)gr * H2 + gc + 64) = o1;
    }
}

// ---------------- GEMM2: 128x128 tile, BK=16, dbuf; optional fused y/z projections ----------------
__global__ __launch_bounds__(256) void k_gemm2(const float* __restrict__ H1, const float* __restrict__ Ws2,
        const float* __restrict__ bs2, const float* __restrict__ gbn, const float* __restrict__ bbn,
        const float* __restrict__ rmbn, const float* __restrict__ rvbn, int l, float* __restrict__ Xout,
        const float* __restrict__ Wrel, const float* __restrict__ Wroot,
        float* __restrict__ Y, float* __restrict__ Z) {
    __shared__ float As[2][16][132];
    __shared__ float Bs[2][16][132];
    const float* W2 = Ws2 + (size_t)l * H2 * HID;
    const float* b2 = bs2 + l * HID;
    const float* g  = gbn + l * HID;
    const float* be = bbn + l * HID;
    const float* rm = rmbn + l * HID;
    const float* rv = rvbn + l * HID;
    int bid = blockIdx.x;
    int wg = (bid & 7) * 64 + (bid >> 3);
    const int mbase = wg * 128;
    const int tid = threadIdx.x;
    const int srow = tid >> 1;
    const int sk   = (tid & 1) * 8;
    const int bk   = tid >> 4;
    const int bc   = (tid & 15) * 4;
    const int ty = tid >> 4;
    const int tx = tid & 15;
    v2f acc[8][4] = {};
    const float* hr = H1 + (size_t)(mbase + srow) * H2 + sk;
    float4 ph0, ph1, pw0, pw1;
    ph0 = *(const float4*)(hr);     ph1 = *(const float4*)(hr + 4);
    {
        const float* wrow = W2 + (size_t)bk * HID;
        pw0 = *(const float4*)(wrow + bc); pw1 = *(const float4*)(wrow + bc + 64);
    }
    As[0][sk + 0][srow] = ph0.x;
    As[0][sk + 1][srow] = ph0.y;
    As[0][sk + 2][srow] = ph0.z;
    As[0][sk + 3][srow] = ph0.w;
    As[0][sk + 4][srow] = ph1.x;
    As[0][sk + 5][srow] = ph1.y;
    As[0][sk + 6][srow] = ph1.z;
    As[0][sk + 7][srow] = ph1.w;
    *(float4*)&Bs[0][bk][bc]      = pw0;
    *(float4*)&Bs[0][bk][bc + 64] = pw1;
    __syncthreads();
    int cur = 0;
    for (int kt = 0; kt < H2; kt += 16) {
        const int nxt = kt + 16;
        if (nxt < H2) {
            ph0 = *(const float4*)(hr + nxt);     ph1 = *(const float4*)(hr + nxt + 4);
            const float* wrow = W2 + (size_t)(nxt + bk) * HID;
            pw0 = *(const float4*)(wrow + bc); pw1 = *(const float4*)(wrow + bc + 64);
        }
        #pragma unroll
        for (int kk = 0; kk < 16; ++kk) {
            const float4 aA = *(const float4*)&As[cur][kk][ty * 8];
            const float4 aB = *(const float4*)&As[cur][kk][ty * 8 + 4];
            const float4 b0 = *(const float4*)&Bs[cur][kk][tx * 4];
            const float4 b1v = *(const float4*)&Bs[cur][kk][tx * 4 + 64];
            v2f b00; b00[0] = b0.x;  b00[1] = b0.y;
            v2f b01; b01[0] = b0.z;  b01[1] = b0.w;
            v2f b10; b10[0] = b1v.x; b10[1] = b1v.y;
            v2f b11; b11[0] = b1v.z; b11[1] = b1v.w;
            const float arr[8] = {aA.x, aA.y, aA.z, aA.w, aB.x, aB.y, aB.z, aB.w};
            #pragma unroll
            for (int i = 0; i < 8; ++i) {
                v2f ai; ai[0] = arr[i]; ai[1] = arr[i];
                acc[i][0] = __builtin_elementwise_fma(ai, b00, acc[i][0]);
                acc[i][1] = __builtin_elementwise_fma(ai, b01, acc[i][1]);
                acc[i][2] = __builtin_elementwise_fma(ai, b10, acc[i][2]);
                acc[i][3] = __builtin_elementwise_fma(ai, b11, acc[i][3]);
            }
        }
        if (nxt < H2) {
            const int nb = cur ^ 1;
            As[nb][sk + 0][srow] = ph0.x;
            As[nb][sk + 1][srow] = ph0.y;
            As[nb][sk + 2][srow] = ph0.z;
            As[nb][sk + 3][srow] = ph0.w;
            As[nb][sk + 4][srow] = ph1.x;
            As[nb][sk + 5][srow] = ph1.y;
            As[nb][sk + 6][srow] = ph1.z;
            As[nb][sk + 7][srow] = ph1.w;
            *(float4*)&Bs[nb][bk][bc]      = pw0;
            *(float4*)&Bs[nb][bk][bc + 64] = pw1;
            __syncthreads();
        }
        cur ^= 1;
    }
    const int gc = tx * 4;
    float bb[8], iv[8], gg[8], rr[8], ee[8];
    #pragma unroll
    for (int j = 0; j < 8; ++j) {
        int c = (j < 4) ? (gc + j) : (gc + 60 + j);
        bb[j] = b2[c];
        iv[j] = __fdiv_rn(1.0f, __fsqrt_rn(__fadd_rn(rv[c], 1e-5f)));
        gg[j] = g[c];
        rr[j] = rm[c];
        ee[j] = be[c];
    }
    float wrl[8], wol[8];
    if (Y) {
        #pragma unroll
        for (int j = 0; j < 8; ++j) {
            int c = (j < 4) ? (gc + j) : (gc + 60 + j);
            wrl[j] = Wrel[c];
            wol[j] = Wroot[c];
        }
    }
    #pragma unroll
    for (int i = 0; i < 8; ++i) {
        const int gr = mbase + ty * 8 + i;
        float cv[8] = {acc[i][0][0], acc[i][0][1], acc[i][1][0], acc[i][1][1],
                       acc[i][2][0], acc[i][2][1], acc[i][3][0], acc[i][3][1]};
        float r[8];
        #pragma unroll
        for (int j = 0; j < 8; ++j) {
            float t = __fadd_rn(cv[j], bb[j]);
            t = __fsub_rn(t, rr[j]); t = __fmul_rn(t, iv[j]);
            t = __fmul_rn(t, gg[j]); t = __fadd_rn(t, ee[j]);
            r[j] = fmaxf(t, 0.f);
        }
        float4 o0; o0.x = r[0]; o0.y = r[1]; o0.z = r[2]; o0.w = r[3];
        float4 o1; o1.x = r[4]; o1.y = r[5]; o1.z = r[6]; o1.w = r[7];
        *(float4*)(Xout + (size_t)gr * HID + gc)      = o0;
        *(float4*)(Xout + (size_t)gr * HID + gc + 64) = o1;
        if (Y) {
            // per-row projections: reduce across the 16 tx lanes (contiguous within wave)
            float py = __fmul_rn(r[0], wrl[0]);
            float pz = __fmul_rn(r[0], wol[0]);
            #pragma unroll
            for (int j = 1; j < 8; ++j) {
                py = __fmaf_rn(r[j], wrl[j], py);
                pz = __fmaf_rn(r[j], wol[j], pz);
            }
            #pragma unroll
            for (int off = 1; off <= 8; off <<= 1) {
                py += __shfl_xor(py, off);
                pz += __shfl_xor(pz, off);
            }
            if (tx == 0) { Y[gr] = py; Z[gr] = pz; }
        }
    }
}

// ---------------- fused score + top-K selection: wsel[n] = selected ? s : 0 ----------------
__global__ __launch_bounds__(512) void k_selscore(const float* __restrict__ Y, const float* __restrict__ Z,
        const int* __restrict__ row_start, const int* __restrict__ csr_src,
        const float* __restrict__ brel, float* __restrict__ WSEL) {
    __shared__ unsigned key[512];
    const int b = blockIdx.x, t = threadIdx.x;
    const int n = b * NNODE + t;
    int beg = row_start[n], end = row_start[n + 1];
    float p1 = 0.f;
    for (int p = beg; p < end; ++p) p1 = __fadd_rn(p1, Y[csr_src[p]]);
    float pp = __fadd_rn(__fadd_rn(p1, brel[0]), Z[n]);
    const float PC = 7.90531110763549805f;   // XLA fast-tanh input clamp -> plateau tie class
    float s;
    if (pp >= PC)       s = 1.0f;
    else if (pp <= -PC) s = -1.0f;
    else                s = (float)tanh((double)pp);
    unsigned u = __float_as_uint(s);
    unsigned o = (u & 0x80000000u) ? ~u : (u | 0x80000000u);
    key[t] = o;
    __syncthreads();
    int rank = 0;
    for (int j = 0; j < NNODE; ++j) {
        unsigned kj = key[j];
        rank += (int)((kj > o) || (kj == o && j < t));
    }
    WSEL[n] = (rank < KSEL) ? s : 0.0f;
}

// ---------------- weighted partial sums: 4 blocks/graph x 2 halves ----------------
__global__ __launch_bounds__(256) void k_wsum(const float* __restrict__ X,
        const float* __restrict__ WSEL, double* __restrict__ PB) {
    __shared__ float wl[128];
    const int blk = blockIdx.x;          // g*4 + q
    const int g = blk >> 2, q = blk & 3;
    const int t = threadIdx.x;
    const int col = t & 127, half = t >> 7;
    if (t < 128) wl[t] = WSEL[g * NNODE + q * 128 + t];
    __syncthreads();
    const int lr0 = half * 64;
    const float* xb = X + ((size_t)(g * NNODE + q * 128 + lr0)) * HID + col;
    double acc = 0.0;
    #pragma unroll 4
    for (int i = 0; i < 64; ++i) {
        acc += (double)xb[(size_t)i * HID] * (double)wl[lr0 + i];
    }
    PB[((size_t)blk * 2 + half) * 128 + col] = acc;
}

// ---------------- combine partials + head ----------------
__global__ __launch_bounds__(128) void k_headc(const double* __restrict__ PB,
        const float* __restrict__ W1, const float* __restrict__ b1,
        const float* __restrict__ gh, const float* __restrict__ beh,
        const float* __restrict__ rmh, const float* __restrict__ rvh,
        const float* __restrict__ W2, const float* __restrict__ b2,
        float* __restrict__ EMB, float* __restrict__ LOGITS) {
    __shared__ double embs[128];
    __shared__ double hbuf[128];
    const int b = blockIdx.x, t = threadIdx.x;
    double e = 0.0;
    #pragma unroll
    for (int part = 0; part < 8; ++part) {
        e += PB[((size_t)(b * 4) * 2 + part) * 128 + t];
    }
    EMB[b * HID + t] = (float)e;
    embs[t] = e;
    __syncthreads();
    double a = 0.0;
    for (int k = 0; k < HID; ++k) a += embs[k] * (double)W1[k * HID + t];
    a += (double)b1[t];
    double inv = 1.0 / sqrt((double)rvh[t] + 1e-5);
    a = (a - (double)rmh[t]) * inv * (double)gh[t] + (double)beh[t];
    hbuf[t] = fmax(a, 0.0);
    __syncthreads();
    if (t < OUTC) {
        double a2 = (double)b2[t];
        for (int k = 0; k < HID; ++k) a2 += hbuf[k] * (double)W2[k * OUTC + t];
        LOGITS[b * OUTC + t] = (float)a2;
    }
}

extern "C" void kernel_launch(void* const* d_in, const int* in_sizes, int n_in,
                              void* d_out, int out_size, void* d_ws, size_t ws_size,
                              hipStream_t stream) {
    const float* x     = (const float*)d_in[0];
    const int*   edge  = (const int*)d_in[1];
    const int*   src   = edge;
    const int*   dst   = edge + EDGES;
    const float* epss  = (const float*)d_in[3];
    const float* Ws1   = (const float*)d_in[4];
    const float* bs1   = (const float*)d_in[5];
    const float* g1s   = (const float*)d_in[6];
    const float* be1s  = (const float*)d_in[7];
    const float* rm1s  = (const float*)d_in[8];
    const float* rv1s  = (const float*)d_in[9];
    const float* Ws2   = (const float*)d_in[10];
    const float* bs2   = (const float*)d_in[11];
    const float* gbn   = (const float*)d_in[12];
    const float* bbn   = (const float*)d_in[13];
    const float* rmbn  = (const float*)d_in[14];
    const float* rvbn  = (const float*)d_in[15];
    const float* Wrel  = (const float*)d_in[16];
    const float* brel  = (const float*)d_in[17];
    const float* Wroot = (const float*)d_in[18];
    const float* W_lin1= (const float*)d_in[19];
    const float* b_lin1= (const float*)d_in[20];
    const float* g_h   = (const float*)d_in[21];
    const float* be_h  = (const float*)d_in[22];
    const float* rm_h  = (const float*)d_in[23];
    const float* rv_h  = (const float*)d_in[24];
    const float* W_lin2= (const float*)d_in[25];
    const float* b_lin2= (const float*)d_in[26];

    char* ws = (char*)d_ws;
    float*  x_cur    = (float*) (ws);                    // 32 MB
    float*  xin      = (float*) (ws + 33554432);         // 32 MB
    float*  h1       = (float*) (ws + 67108864);         // 64 MB
    float*  wsel     = (float*) (ws + 134217728);        // 256 KB
    float*  ybuf     = (float*) (ws + 134479872);        // 256 KB
    float*  zbuf     = (float*) (ws + 134742016);        // 256 KB
    double* pbuf     = (double*)(ws + 135004160);        // 1 MB
    int*    row_start= (int*)   (ws + 136052736);        // 280 KB (NT_+1 ints)
    int*    csr2     = (int*)   (ws + 136339456);        // 4 MB

    float* emb    = (float*)d_out;
    float* logits = (float*)d_out + BGRAPH * HID;

    // ---- fused per-graph CSR build ----
    k_csr<<<BGRAPH, 512, 0, stream>>>(src, dst, row_start, csr2);

    // ---- layer 0 ----
    k_aggcomb<<<NT_ / 8, 256, 0, stream>>>(x, row_start, csr2, epss, 0, xin);
    k_gemm1<<<1024, 256, 0, stream>>>(xin, Ws1, bs1, g1s, be1s, rm1s, rv1s, 0, h1);
    k_gemm2<<<512, 256, 0, stream>>>(h1, Ws2, bs2, gbn, bbn, rmbn, rvbn, 0, x_cur,
                                     nullptr, nullptr, nullptr, nullptr);
    // ---- layer 1 (fused y/z projections in epilogue) ----
    k_aggcomb<<<NT_ / 8, 256, 0, stream>>>(x_cur, row_start, csr2, epss, 1, xin);
    k_gemm1<<<1024, 256, 0, stream>>>(xin, Ws1, bs1, g1s, be1s, rm1s, rv1s, 1, h1);
    k_gemm2<<<512, 256, 0, stream>>>(h1, Ws2, bs2, gbn, bbn, rmbn, rvbn, 1, x_cur,
                                     Wrel, Wroot, ybuf, zbuf);
    // ---- selection + pool + head ----
    k_selscore<<<BGRAPH, 512, 0, stream>>>(ybuf, zbuf, row_start, csr2, brel, wsel);
    k_wsum<<<4 * BGRAPH, 256, 0, stream>>>(x_cur, wsel, pbuf);
    k_headc<<<BGRAPH, 128, 0, stream>>>(pbuf, W_lin1, b_lin1, g_h, be_h, rm_h, rv_h,
                                        W_lin2, b_lin2, emb, logits);
}